// Round 12
// baseline (169.977 us; speedup 1.0000x reference)
//
#include <hip/hip_runtime.h>
#include <hip/hip_bf16.h>

#define N_NODES 100000
#define N_EDGES 1600000
#define D 128

#define NBINS 196       // ceil(100000 / 512) node bins
#define BINSHIFT 9      // 512 nodes per bin
#define EPB 8192        // edges per region (k_bin2 block)
#define RBLK 196        // edge regions
#define EBUF_CAP 8960   // LDS staging cap per bin

// k_mid block layout: [0,196) binsort, [196,204) W image, [204,1767) X cvt-sliced
#define MID_SORT_BLOCKS 196
#define MID_W_BLOCKS 8
#define MID_CVT_BLOCKS 1563    // ceil(100000*8 / 512) (n,slice) pairs

#define SLICE_U 800000         // uints per slice (100000 nodes x 8 uints)
#define SLICE_S 1600000        // shorts per slice

#define PADK 136

typedef __bf16 bf16x8 __attribute__((ext_vector_type(8)));
typedef short short8 __attribute__((ext_vector_type(8)));
typedef float f32x4 __attribute__((ext_vector_type(4)));

__device__ __forceinline__ unsigned short f2bf(float f) {
  union { float f; unsigned u; } c; c.f = f;
  unsigned u = c.u;
  u += 0x7FFFu + ((u >> 16) & 1u);   // round-to-nearest-even
  return (unsigned short)(u >> 16);
}
__device__ __forceinline__ float bflo(unsigned u) {
  union { unsigned u; float f; } c; c.u = u << 16; return c.f;
}
__device__ __forceinline__ float bfhi(unsigned u) {
  union { unsigned u; float f; } c; c.u = u & 0xFFFF0000u; return c.f;
}

// ============ k_bin2: atomic-free edge binning (round-10 proven) ============
__launch_bounds__(512)
__global__ void k_bin2(const int* __restrict__ esrc, const int* __restrict__ edst,
                       unsigned* __restrict__ binbuf, int* __restrict__ cntmatT,
                       int* __restrict__ startmatT) {
  __shared__ unsigned lbuf[EPB];       // 32 KB
  __shared__ int cnt[NBINS];
  __shared__ int base[NBINS];
  __shared__ int cur[NBINS];
  __shared__ int scanb[256];
  const int b = blockIdx.x, t = threadIdx.x;
  const int e0 = b * EPB;
  const int ne = min(EPB, N_EDGES - e0);

  for (int i = t; i < NBINS; i += 512) { cnt[i] = 0; cur[i] = 0; }
  __syncthreads();
  for (int i = t; i < ne; i += 512)
    atomicAdd(&cnt[edst[e0 + i] >> BINSHIFT], 1);
  __syncthreads();
  if (t < 256) scanb[t] = (t < NBINS) ? cnt[t] : 0;
  __syncthreads();
  for (int d = 1; d < 256; d <<= 1) {
    int x = 0;
    if (t < 256 && t >= d) x = scanb[t - d];
    __syncthreads();
    if (t < 256) scanb[t] += x;
    __syncthreads();
  }
  if (t < NBINS) base[t] = scanb[t] - cnt[t];
  __syncthreads();
  for (int i = t; i < ne; i += 512) {
    int d = edst[e0 + i];
    int s = esrc[e0 + i];
    int bi = d >> BINSHIFT;
    int pos = base[bi] + atomicAdd(&cur[bi], 1);
    lbuf[pos] = ((unsigned)(d & 511) << 17) | (unsigned)s;
  }
  __syncthreads();
  uint4* dst4 = (uint4*)(binbuf + (size_t)b * EPB);
  const uint4* src4 = (const uint4*)lbuf;
  for (int i = t; i < EPB / 4; i += 512) dst4[i] = src4[i];
  if (t < NBINS) {
    cntmatT[t * RBLK + b] = cnt[t];     // [bin][region]
    startmatT[t * RBLK + b] = base[t];
  }
}

// ============ k_mid: fused binsort + W image + X cvt (SLICED) ===============
__launch_bounds__(512)
__global__ void k_mid(const unsigned* __restrict__ binbuf, const int* __restrict__ cntmatT,
                      const int* __restrict__ startmatT,
                      int* __restrict__ srt, int* __restrict__ deg, int* __restrict__ offs,
                      const float* __restrict__ X, unsigned short* __restrict__ Xb,
                      const float* __restrict__ W1, const float* __restrict__ W2,
                      unsigned short* __restrict__ Wimg) {
  const int b = blockIdx.x, t = threadIdx.x;

  if (b < MID_SORT_BLOCKS) {
    // ---- per-bin counting sort; emits deg/offs (START), dense srt ----
    __shared__ unsigned ebuf[EBUF_CAP];
    __shared__ int hist[512];
    __shared__ int scn[512];
    __shared__ int rcnt[RBLK];
    __shared__ int roff[RBLK];
    __shared__ int eoff[RBLK];
    __shared__ int colsc[256];

    for (int r = t; r < RBLK; r += 512) {
      rcnt[r] = cntmatT[b * RBLK + r];
      roff[r] = startmatT[b * RBLK + r];
    }
    int cs = 0;
    if (t < NBINS) {
      const uint4* row = (const uint4*)(cntmatT + t * RBLK);
#pragma unroll 7
      for (int j = 0; j < RBLK / 4; ++j) {
        uint4 v = row[j];
        cs += (int)(v.x + v.y + v.z + v.w);
      }
    }
    if (t < 256) colsc[t] = (t < NBINS) ? cs : 0;
    __syncthreads();
    for (int d = 1; d < 256; d <<= 1) {
      int x = 0;
      if (t < 256 && t >= d) x = colsc[t - d];
      __syncthreads();
      if (t < 256) colsc[t] += x;
      __syncthreads();
    }
    const int mytotal = colsc[b] - ((b == 0) ? 0 : colsc[b - 1]);
    const int gbase = (b == 0) ? 0 : colsc[b - 1];

    if (t < 256) scn[t] = (t < RBLK) ? rcnt[t] : 0;
    __syncthreads();
    for (int d = 1; d < 256; d <<= 1) {
      int x = 0;
      if (t < 256 && t >= d) x = scn[t - d];
      __syncthreads();
      if (t < 256) scn[t] += x;
      __syncthreads();
    }
    if (t < RBLK) eoff[t] = scn[t] - rcnt[t];
    __syncthreads();

    const int wv = t >> 6, ln = t & 63;
    for (int r = wv; r < RBLK; r += 8) {
      const unsigned* src = binbuf + (size_t)r * EPB + roff[r];
      int c = rcnt[r], o = eoff[r];
      for (int i = ln; i < c; i += 64) ebuf[o + i] = src[i];
    }
    hist[t] = 0;
    __syncthreads();

    for (int i = t; i < mytotal; i += 512)
      atomicAdd(&hist[ebuf[i] >> 17], 1);
    __syncthreads();
    int v = hist[t];
    scn[t] = v;
    __syncthreads();
    for (int d = 1; d < 512; d <<= 1) {
      int x = (t >= d) ? scn[t - d] : 0;
      __syncthreads();
      scn[t] += x;
      __syncthreads();
    }
    int n = (b << BINSHIFT) + t;
    if (n < N_NODES) {
      deg[n] = v;
      offs[n] = gbase + scn[t] - v;   // segment start, dense srt
    }
    hist[t] = scn[t] - v;             // write cursor
    __syncthreads();
    for (int i = t; i < mytotal; i += 512) {
      unsigned e = ebuf[i];
      int pos = atomicAdd(&hist[e >> 17], 1);
      srt[gbase + pos] = (int)(e & 0x1FFFFu);
    }
    return;
  }
  if (b < MID_SORT_BLOCKS + MID_W_BLOCKS) {
    int bb = b - MID_SORT_BLOCKS;
    const float* W = (bb & 4) ? W2 : W1;
    unsigned short* img = Wimg + ((bb & 4) ? 128 * PADK : 0);
    int k0 = (bb & 3) * 32;
#pragma unroll
    for (int it = 0; it < 8; ++it) {
      int idx = it * 512 + t;                 // 4096 entries: 32 k x 128 n
      int k = k0 + (idx >> 7), n = idx & 127;
      img[n * PADK + k] = f2bf(W[k * 128 + n]);
    }
    return;
  }
  // ---- X f32 -> bf16 SLICED: thread handles (node n, slice sl) = 16 cols ----
  int idx = (b - MID_SORT_BLOCKS - MID_W_BLOCKS) * 512 + t;
  if (idx >= N_NODES * 8) return;
  int n = idx >> 3, sl = idx & 7;
  const float4* p = (const float4*)(X + (size_t)n * D + sl * 16);
  float4 a0 = p[0], a1 = p[1], a2 = p[2], a3 = p[3];
  short8 s0, s1;
  s0[0] = f2bf(a0.x); s0[1] = f2bf(a0.y); s0[2] = f2bf(a0.z); s0[3] = f2bf(a0.w);
  s0[4] = f2bf(a1.x); s0[5] = f2bf(a1.y); s0[6] = f2bf(a1.z); s0[7] = f2bf(a1.w);
  s1[0] = f2bf(a2.x); s1[1] = f2bf(a2.y); s1[2] = f2bf(a2.z); s1[3] = f2bf(a2.w);
  s1[4] = f2bf(a3.x); s1[5] = f2bf(a3.y); s1[6] = f2bf(a3.z); s1[7] = f2bf(a3.w);
  unsigned short* dst = Xb + (size_t)sl * SLICE_S + (size_t)n * 16;
  *(short8*)dst = s0;
  *(short8*)(dst + 8) = s1;
}

// ============ k_gather_sl: XCD-sliced gather ================================
// blockIdx%8 = slice -> lands on one XCD (round-robin dispatch); that XCD
// only touches its 3.2MB slice of Xb -> L2-resident after warm.
// 8-lane groups: group reads a 32B row-slice per edge; 4-deep unroll.
__launch_bounds__(512)
__global__ void k_gather_sl(const unsigned* __restrict__ Xs,
                            const int* __restrict__ deg, const int* __restrict__ offs,
                            const int* __restrict__ srt, unsigned* __restrict__ h0s) {
  const int sl = blockIdx.x & 7;
  const int chunk = blockIdx.x >> 3;
  const int t = threadIdx.x;
  const int G = t >> 3, l8 = t & 7;     // 64 groups of 8 lanes
  const unsigned* Xsl = Xs + (size_t)sl * SLICE_U;
  unsigned* h0sl = h0s + (size_t)sl * SLICE_U;

#pragma unroll
  for (int j = 0; j < 4; ++j) {
    int node = chunk * 256 + j * 64 + G;   // wave writes 8 consecutive nodes
    if (node >= N_NODES) break;
    unsigned u = Xsl[node * 8 + l8];
    float hx = bflo(u), hy = bfhi(u);
    int e = offs[node];
    int end = e + deg[node];
    for (; e + 4 <= end; e += 4) {
      int s0 = srt[e], s1 = srt[e + 1], s2 = srt[e + 2], s3 = srt[e + 3];
      unsigned u0 = Xsl[s0 * 8 + l8];
      unsigned u1 = Xsl[s1 * 8 + l8];
      unsigned u2 = Xsl[s2 * 8 + l8];
      unsigned u3 = Xsl[s3 * 8 + l8];
      hx += bflo(u0); hy += bfhi(u0);
      hx += bflo(u1); hy += bfhi(u1);
      hx += bflo(u2); hy += bfhi(u2);
      hx += bflo(u3); hy += bfhi(u3);
    }
    for (; e < end; ++e) {
      unsigned u0 = Xsl[srt[e] * 8 + l8];
      hx += bflo(u0); hy += bfhi(u0);
    }
    h0sl[node * 8 + l8] = ((unsigned)f2bf(hy) << 16) | f2bf(hx);
  }
}

// ============ k_mlp2: proven round-7 structure; A-frags from SLICED h0 ======
#define BR2 128

__launch_bounds__(512, 4)
__global__ void k_mlp2(const unsigned short* __restrict__ h0,   // sliced layout
                       const unsigned short* __restrict__ Wimg,
                       const float* __restrict__ b1v, const float* __restrict__ b2v,
                       float* __restrict__ out) {
  __shared__ __attribute__((aligned(16))) unsigned short lW[128 * PADK];
  __shared__ __attribute__((aligned(16))) unsigned short lH[BR2 * PADK];

  const int t = threadIdx.x;
  const int wave = t >> 6, lane = t & 63;
  const int lr = lane & 15, lg = lane >> 4;
  const int row0 = blockIdx.x * BR2;
  const int wrow = row0 + wave * 16;

  const uint4* wi = (const uint4*)Wimg;
  uint4* lw = (uint4*)lW;

  // stage W1 image (2176 uint4)
  for (int i = t; i < 2176; i += 512) lw[i] = wi[i];

  // A fragments from sliced h0: cols kb*32+lg*8 -> slice 2kb+(lg>>1), off (lg&1)*8
  bf16x8 a[4];
#pragma unroll
  for (int kb = 0; kb < 4; ++kb) {
    int r = wrow + lr;
    if (r >= N_NODES) r = N_NODES - 1;
    int slc = kb * 2 + (lg >> 1);
    a[kb] = __builtin_bit_cast(bf16x8,
        *(const short8*)(h0 + (size_t)slc * SLICE_S + (size_t)r * 16 + (lg & 1) * 8));
  }

  f32x4 acc[8];
#pragma unroll
  for (int nc = 0; nc < 8; ++nc) {
    float bb = b1v[nc * 16 + lr];
    acc[nc] = (f32x4){bb, bb, bb, bb};
  }

  __syncthreads();   // W1 staged

  // GEMM1
#pragma unroll
  for (int nc = 0; nc < 8; ++nc) {
#pragma unroll
    for (int kb = 0; kb < 4; ++kb) {
      bf16x8 b = *(const bf16x8*)&lW[(nc * 16 + lr) * PADK + kb * 32 + lg * 8];
      acc[nc] = __builtin_amdgcn_mfma_f32_16x16x32_bf16(a[kb], b, acc[nc], 0, 0, 0);
    }
  }

  __syncthreads();   // everyone done reading W1

  // restage W2
  {
    const uint4* wi2 = (const uint4*)Wimg + 2176;
    for (int i = t; i < 2176; i += 512) lw[i] = wi2[i];
  }

  // ReLU -> h1 into own stripe (intra-wave dependency only)
#pragma unroll
  for (int nc = 0; nc < 8; ++nc) {
#pragma unroll
    for (int r = 0; r < 4; ++r) {
      float v = acc[nc][r];
      v = v > 0.f ? v : 0.f;
      lH[(wave * 16 + lg * 4 + r) * PADK + nc * 16 + lr] = f2bf(v);
    }
  }

  __syncthreads();   // W2 staged

  bf16x8 a2[4];
#pragma unroll
  for (int kb = 0; kb < 4; ++kb)
    a2[kb] = *(const bf16x8*)&lH[(wave * 16 + lr) * PADK + kb * 32 + lg * 8];

#pragma unroll
  for (int nc = 0; nc < 8; ++nc) {
    float bb = b2v[nc * 16 + lr];
    acc[nc] = (f32x4){bb, bb, bb, bb};
  }

  // GEMM2
#pragma unroll
  for (int nc = 0; nc < 8; ++nc) {
#pragma unroll
    for (int kb = 0; kb < 4; ++kb) {
      bf16x8 b = *(const bf16x8*)&lW[(nc * 16 + lr) * PADK + kb * 32 + lg * 8];
      acc[nc] = __builtin_amdgcn_mfma_f32_16x16x32_bf16(a2[kb], b, acc[nc], 0, 0, 0);
    }
  }

  // store f32
#pragma unroll
  for (int nc = 0; nc < 8; ++nc) {
#pragma unroll
    for (int r = 0; r < 4; ++r) {
      int row = wrow + lg * 4 + r;
      if (row < N_NODES) out[(size_t)row * D + nc * 16 + lr] = acc[nc][r];
    }
  }
}

// ================= old CSR build (fallback path, end-semantics offs) ========

__global__ void k_hist(const int* __restrict__ dst, int* __restrict__ deg) {
  int i = blockIdx.x * 256 + threadIdx.x;
  if (i < N_EDGES) atomicAdd(&deg[dst[i]], 1);
}

__global__ void k_scan1(const int* __restrict__ deg, int* __restrict__ offs,
                        int* __restrict__ bsum) {
  __shared__ int s[1024];
  int t = threadIdx.x;
  int i = blockIdx.x * 1024 + t;
  int v = (i < N_NODES) ? deg[i] : 0;
  s[t] = v;
  __syncthreads();
  for (int d = 1; d < 1024; d <<= 1) {
    int x = (t >= d) ? s[t - d] : 0;
    __syncthreads();
    s[t] += x;
    __syncthreads();
  }
  if (i < N_NODES) offs[i] = s[t] - v;
  if (t == 1023) bsum[blockIdx.x] = s[t];
}

__global__ void k_scan2(int* __restrict__ bsum) {
  __shared__ int s[128];
  int t = threadIdx.x;
  int v = (t < 98) ? bsum[t] : 0;
  s[t] = v;
  __syncthreads();
  for (int d = 1; d < 128; d <<= 1) {
    int x = (t >= d) ? s[t - d] : 0;
    __syncthreads();
    s[t] += x;
    __syncthreads();
  }
  if (t < 98) bsum[t] = s[t] - v;
}

__global__ void k_scan3(int* __restrict__ offs, const int* __restrict__ bsum) {
  int i = blockIdx.x * 1024 + threadIdx.x;
  if (i < N_NODES) offs[i] += bsum[blockIdx.x];
}

__global__ void k_bucket(const int* __restrict__ src, const int* __restrict__ dst,
                         int* __restrict__ offs, int* __restrict__ srt) {
  int i = blockIdx.x * 256 + threadIdx.x;
  if (i < N_EDGES) {
    int pos = atomicAdd(&offs[dst[i]], 1);
    srt[pos] = src[i];
  }
}

__global__ void k_gather(const float* __restrict__ X, const int* __restrict__ deg,
                         const int* __restrict__ offs, const int* __restrict__ srt,
                         float* __restrict__ out) {
  int node = blockIdx.x * 4 + (threadIdx.x >> 6);
  int lane = threadIdx.x & 63;
  const float2* X2 = (const float2*)X;
  float2 h = X2[(size_t)node * 64 + lane];
  int end = offs[node];
  int dg = deg[node];
  for (int e = end - dg; e < end; ++e) {
    int s = srt[e];
    float2 x = X2[(size_t)s * 64 + lane];
    h.x += x.x; h.y += x.y;
  }
  ((float2*)out)[(size_t)node * 64 + lane] = h;
}

#define BR 256

__launch_bounds__(512, 1)
__global__ void k_mlp(const float* __restrict__ h0,
                      const float* __restrict__ W1, const float* __restrict__ b1,
                      const float* __restrict__ W2, const float* __restrict__ b2,
                      float* __restrict__ out) {
  __shared__ __attribute__((aligned(16))) unsigned short lW[2 * 128 * PADK];
  __shared__ __attribute__((aligned(16))) unsigned short lH[BR * PADK];

  const int t = threadIdx.x;
  const int wave = t >> 6, lane = t & 63;
  const int lr = lane & 15, lg = lane >> 4;
  const int row0 = blockIdx.x * BR;
  const int wrow = row0 + wave * 32;

  for (int i = t; i < 128 * 128; i += 512) {
    int k = i >> 7, n = i & 127;
    lW[n * PADK + k] = f2bf(W1[i]);
    lW[128 * PADK + n * PADK + k] = f2bf(W2[i]);
  }

  bf16x8 a[2][4];
#pragma unroll
  for (int tr = 0; tr < 2; ++tr) {
#pragma unroll
    for (int kb = 0; kb < 4; ++kb) {
      int r = wrow + tr * 16 + lr;
      if (r >= N_NODES) r = N_NODES - 1;
      const float4* p = (const float4*)(h0 + (size_t)r * D + kb * 32 + lg * 8);
      float4 f0 = p[0], f1 = p[1];
      short8 s;
      s[0] = f2bf(f0.x); s[1] = f2bf(f0.y); s[2] = f2bf(f0.z); s[3] = f2bf(f0.w);
      s[4] = f2bf(f1.x); s[5] = f2bf(f1.y); s[6] = f2bf(f1.z); s[7] = f2bf(f1.w);
      a[tr][kb] = __builtin_bit_cast(bf16x8, s);
    }
  }

  f32x4 acc[2][8];
#pragma unroll
  for (int nc = 0; nc < 8; ++nc) {
    float bb = b1[nc * 16 + lr];
#pragma unroll
    for (int tr = 0; tr < 2; ++tr) acc[tr][nc] = (f32x4){bb, bb, bb, bb};
  }

  __syncthreads();

#pragma unroll
  for (int nc = 0; nc < 8; ++nc) {
#pragma unroll
    for (int kb = 0; kb < 4; ++kb) {
      bf16x8 b = *(const bf16x8*)&lW[(nc * 16 + lr) * PADK + kb * 32 + lg * 8];
#pragma unroll
      for (int tr = 0; tr < 2; ++tr)
        acc[tr][nc] = __builtin_amdgcn_mfma_f32_16x16x32_bf16(a[tr][kb], b, acc[tr][nc], 0, 0, 0);
    }
  }

#pragma unroll
  for (int tr = 0; tr < 2; ++tr) {
#pragma unroll
    for (int nc = 0; nc < 8; ++nc) {
#pragma unroll
      for (int r = 0; r < 4; ++r) {
        float v = acc[tr][nc][r];
        v = v > 0.f ? v : 0.f;
        int lrow = wave * 32 + tr * 16 + lg * 4 + r;
        lH[lrow * PADK + nc * 16 + lr] = f2bf(v);
      }
    }
  }

  __syncthreads();

  bf16x8 a2[2][4];
#pragma unroll
  for (int tr = 0; tr < 2; ++tr) {
#pragma unroll
    for (int kb = 0; kb < 4; ++kb)
      a2[tr][kb] = *(const bf16x8*)&lH[(wave * 32 + tr * 16 + lr) * PADK + kb * 32 + lg * 8];
  }

#pragma unroll
  for (int nc = 0; nc < 8; ++nc) {
    float bb = b2[nc * 16 + lr];
#pragma unroll
    for (int tr = 0; tr < 2; ++tr) acc[tr][nc] = (f32x4){bb, bb, bb, bb};
  }

#pragma unroll
  for (int nc = 0; nc < 8; ++nc) {
#pragma unroll
    for (int kb = 0; kb < 4; ++kb) {
      bf16x8 b = *(const bf16x8*)&lW[128 * PADK + (nc * 16 + lr) * PADK + kb * 32 + lg * 8];
#pragma unroll
      for (int tr = 0; tr < 2; ++tr)
        acc[tr][nc] = __builtin_amdgcn_mfma_f32_16x16x32_bf16(a2[tr][kb], b, acc[tr][nc], 0, 0, 0);
    }
  }

#pragma unroll
  for (int tr = 0; tr < 2; ++tr) {
#pragma unroll
    for (int nc = 0; nc < 8; ++nc) {
#pragma unroll
      for (int r = 0; r < 4; ++r) {
        int row = wrow + tr * 16 + lg * 4 + r;
        if (row < N_NODES) out[(size_t)row * D + nc * 16 + lr] = acc[tr][nc][r];
      }
    }
  }
}

extern "C" void kernel_launch(void* const* d_in, const int* in_sizes, int n_in,
                              void* d_out, int out_size, void* d_ws, size_t ws_size,
                              hipStream_t stream) {
  const float* X  = (const float*)d_in[0];
  const float* W1 = (const float*)d_in[1];
  const float* b1 = (const float*)d_in[2];
  const float* W2 = (const float*)d_in[3];
  const float* b2 = (const float*)d_in[4];
  const int* esrc = (const int*)d_in[5];
  const int* edst = (const int*)d_in[6];
  float* out = (float*)d_out;

  char* ws = (char*)d_ws;
  // round-10 proven layout; Xb/h0b now hold the SLICED images
  int* deg      = (int*)(ws);                          // 400,000 B
  int* offs     = (int*)(ws + 400000);                 // 400,000 B
  int* srt      = (int*)(ws + 800000);                 // 6,400,000 B -> 7,200,000
  unsigned short* Xb  = (unsigned short*)(ws + 7200000);   // 25.6 MB sliced
  unsigned short* h0b = (unsigned short*)(ws + 32800000);  // 25.6 MB sliced
  unsigned* binbuf = (unsigned*)(ws + 32800000);           // 6,422,528 B (alias, dead by gather)
  int* cntmatT   = (int*)(ws + 32800000 + 6422528);        // 153,664 B
  int* startmatT = (int*)(ws + 32800000 + 6422528 + 153664);
  unsigned short* Wimg = (unsigned short*)(ws + 58400000); // 69,632 B
  const size_t NEED = 58469632;

  if (ws_size >= NEED) {
    k_bin2<<<RBLK, 512, 0, stream>>>(esrc, edst, binbuf, cntmatT, startmatT);
    k_mid<<<MID_SORT_BLOCKS + MID_W_BLOCKS + MID_CVT_BLOCKS, 512, 0, stream>>>(
        binbuf, cntmatT, startmatT, srt, deg, offs, X, Xb, W1, W2, Wimg);
    k_gather_sl<<<((N_NODES + 255) / 256) * 8, 512, 0, stream>>>(
        (const unsigned*)Xb, deg, offs, srt, (unsigned*)h0b);
    k_mlp2<<<(N_NODES + BR2 - 1) / BR2, 512, 0, stream>>>(h0b, Wimg, b1, b2, out);
  } else {
    // fallback: proven round-1 pipeline (f32 gather, END-semantics offs)
    int* bsum = (int*)(ws + 800000);
    int* srtF = (int*)(ws + 802048);
    hipMemsetAsync(deg, 0, N_NODES * sizeof(int), stream);
    k_hist  <<<N_EDGES / 256, 256, 0, stream>>>(edst, deg);
    k_scan1 <<<98, 1024, 0, stream>>>(deg, offs, bsum);
    k_scan2 <<<1, 128, 0, stream>>>(bsum);
    k_scan3 <<<98, 1024, 0, stream>>>(offs, bsum);
    k_bucket<<<N_EDGES / 256, 256, 0, stream>>>(esrc, edst, offs, srtF);
    k_gather<<<N_NODES / 4, 256, 0, stream>>>(X, deg, offs, srtF, out);
    k_mlp   <<<(N_NODES + BR - 1) / BR, 512, 0, stream>>>(out, W1, b1, W2, b2, out);
  }
}

// Round 13
// 134.448 us; speedup vs baseline: 1.2643x; 1.2643x over previous
//
#include <hip/hip_runtime.h>
#include <hip/hip_bf16.h>

#define N_NODES 100000
#define N_EDGES 1600000
#define D 128

#define NBINS 196       // ceil(100000 / 512) node bins
#define BINSHIFT 9      // 512 nodes per bin
#define EPB 8192        // edges per region (bin block)
#define RBLK 196        // edge regions
#define EBUF_CAP 8960   // LDS staging cap per bin

// k_head block layout: [0,196) bin, [196,204) W image, [204,3329) X cvt
#define HEAD_W_BLOCKS 8
#define HEAD_CVT_BLOCKS 3125   // 100000*128 / (512*8)

#define PADK 136

typedef __bf16 bf16x8 __attribute__((ext_vector_type(8)));
typedef short short8 __attribute__((ext_vector_type(8)));
typedef float f32x4 __attribute__((ext_vector_type(4)));

__device__ __forceinline__ unsigned short f2bf(float f) {
  union { float f; unsigned u; } c; c.f = f;
  unsigned u = c.u;
  u += 0x7FFFu + ((u >> 16) & 1u);   // round-to-nearest-even
  return (unsigned short)(u >> 16);
}
__device__ __forceinline__ float bflo(unsigned u) {
  union { unsigned u; float f; } c; c.u = u << 16; return c.f;
}
__device__ __forceinline__ float bfhi(unsigned u) {
  union { unsigned u; float f; } c; c.u = u & 0xFFFF0000u; return c.f;
}

// ============ k_head: fused edge binning (FIRST) + W image + X cvt ==========
// (round-11 proven verbatim) Bin blocks overlap with cvt blocks -> head
// makespan ~= max(bin, cvt), not sum. Zero global atomics, zero memset.
__launch_bounds__(512)
__global__ void k_head(const int* __restrict__ esrc, const int* __restrict__ edst,
                       unsigned* __restrict__ binbuf, int* __restrict__ cntmatT,
                       int* __restrict__ startmatT,
                       const float* __restrict__ X, unsigned short* __restrict__ Xb,
                       const float* __restrict__ W1, const float* __restrict__ W2,
                       unsigned short* __restrict__ Wimg) {
  const int b = blockIdx.x, t = threadIdx.x;

  if (b < RBLK) {
    __shared__ unsigned lbuf[EPB];       // 32 KB
    __shared__ int cnt[NBINS];
    __shared__ int base[NBINS];
    __shared__ int cur[NBINS];
    __shared__ int scanb[256];
    const int e0 = b * EPB;
    const int ne = min(EPB, N_EDGES - e0);

    for (int i = t; i < NBINS; i += 512) { cnt[i] = 0; cur[i] = 0; }
    __syncthreads();
    for (int i = t; i < ne; i += 512)
      atomicAdd(&cnt[edst[e0 + i] >> BINSHIFT], 1);
    __syncthreads();
    if (t < 256) scanb[t] = (t < NBINS) ? cnt[t] : 0;
    __syncthreads();
    for (int d = 1; d < 256; d <<= 1) {
      int x = 0;
      if (t < 256 && t >= d) x = scanb[t - d];
      __syncthreads();
      if (t < 256) scanb[t] += x;
      __syncthreads();
    }
    if (t < NBINS) base[t] = scanb[t] - cnt[t];
    __syncthreads();
    for (int i = t; i < ne; i += 512) {
      int d = edst[e0 + i];
      int s = esrc[e0 + i];
      int bi = d >> BINSHIFT;
      int pos = base[bi] + atomicAdd(&cur[bi], 1);
      lbuf[pos] = ((unsigned)(d & 511) << 17) | (unsigned)s;
    }
    __syncthreads();
    // dense stream-out (garbage tail never referenced via counts)
    uint4* dst4 = (uint4*)(binbuf + (size_t)b * EPB);
    const uint4* src4 = (const uint4*)lbuf;
    for (int i = t; i < EPB / 4; i += 512) dst4[i] = src4[i];
    if (t < NBINS) {
      cntmatT[t * RBLK + b] = cnt[t];     // [bin][region]
      startmatT[t * RBLK + b] = base[t];
    }
    return;
  }
  if (b < RBLK + HEAD_W_BLOCKS) {
    int bb = b - RBLK;
    const float* W = (bb & 4) ? W2 : W1;
    unsigned short* img = Wimg + ((bb & 4) ? 128 * PADK : 0);
    int k0 = (bb & 3) * 32;
#pragma unroll
    for (int it = 0; it < 8; ++it) {
      int idx = it * 512 + t;                 // 4096 entries: 32 k x 128 n
      int k = k0 + (idx >> 7), n = idx & 127;
      img[n * PADK + k] = f2bf(W[k * 128 + n]);
    }
    return;
  }
  // ---- X f32 -> bf16 (row-major) ----
  size_t i = ((size_t)(b - RBLK - HEAD_W_BLOCKS) * 512 + t) * 8;
  const float4* p = (const float4*)(X + i);
  float4 a = p[0], c = p[1];
  short8 s;
  s[0] = f2bf(a.x); s[1] = f2bf(a.y); s[2] = f2bf(a.z); s[3] = f2bf(a.w);
  s[4] = f2bf(c.x); s[5] = f2bf(c.y); s[6] = f2bf(c.z); s[7] = f2bf(c.w);
  *(short8*)(Xb + i) = s;
}

// ============ k_sort: per-bin counting sort -> dense srt + deg/offs =========
// (round-10 proven k_mid sort branch, standalone; START-semantics offs)
__launch_bounds__(512)
__global__ void k_sort(const unsigned* __restrict__ binbuf, const int* __restrict__ cntmatT,
                       const int* __restrict__ startmatT,
                       int* __restrict__ srt, int* __restrict__ deg,
                       int* __restrict__ offs) {
  __shared__ unsigned ebuf[EBUF_CAP];
  __shared__ int hist[512];
  __shared__ int scn[512];
  __shared__ int rcnt[RBLK];
  __shared__ int roff[RBLK];
  __shared__ int eoff[RBLK];
  __shared__ int colsc[256];
  const int b = blockIdx.x, t = threadIdx.x;

  for (int r = t; r < RBLK; r += 512) {
    rcnt[r] = cntmatT[b * RBLK + r];
    roff[r] = startmatT[b * RBLK + r];
  }
  // column sums of cntmatT -> per-bin totals (thread t sums bin t's row)
  int cs = 0;
  if (t < NBINS) {
    const uint4* row = (const uint4*)(cntmatT + t * RBLK);
#pragma unroll 7
    for (int j = 0; j < RBLK / 4; ++j) {
      uint4 v = row[j];
      cs += (int)(v.x + v.y + v.z + v.w);
    }
  }
  if (t < 256) colsc[t] = (t < NBINS) ? cs : 0;
  __syncthreads();
  for (int d = 1; d < 256; d <<= 1) {
    int x = 0;
    if (t < 256 && t >= d) x = colsc[t - d];
    __syncthreads();
    if (t < 256) colsc[t] += x;
    __syncthreads();
  }
  const int mytotal = colsc[b] - ((b == 0) ? 0 : colsc[b - 1]);
  const int gbase = (b == 0) ? 0 : colsc[b - 1];

  if (t < 256) scn[t] = (t < RBLK) ? rcnt[t] : 0;
  __syncthreads();
  for (int d = 1; d < 256; d <<= 1) {
    int x = 0;
    if (t < 256 && t >= d) x = scn[t - d];
    __syncthreads();
    if (t < 256) scn[t] += x;
    __syncthreads();
  }
  if (t < RBLK) eoff[t] = scn[t] - rcnt[t];
  __syncthreads();

  // gather this bin's edges from all regions into LDS (wave wv: r ≡ wv mod 8)
  const int wv = t >> 6, ln = t & 63;
  for (int r = wv; r < RBLK; r += 8) {
    const unsigned* src = binbuf + (size_t)r * EPB + roff[r];
    int c = rcnt[r], o = eoff[r];
    for (int i = ln; i < c; i += 64) ebuf[o + i] = src[i];
  }
  hist[t] = 0;
  __syncthreads();

  for (int i = t; i < mytotal; i += 512)
    atomicAdd(&hist[ebuf[i] >> 17], 1);
  __syncthreads();
  int v = hist[t];
  scn[t] = v;
  __syncthreads();
  for (int d = 1; d < 512; d <<= 1) {
    int x = (t >= d) ? scn[t - d] : 0;
    __syncthreads();
    scn[t] += x;
    __syncthreads();
  }
  int n = (b << BINSHIFT) + t;
  if (n < N_NODES) {
    deg[n] = v;
    offs[n] = gbase + scn[t] - v;   // segment start, dense srt
  }
  hist[t] = scn[t] - v;             // write cursor
  __syncthreads();
  for (int i = t; i < mytotal; i += 512) {
    unsigned e = ebuf[i];
    int pos = atomicAdd(&hist[e >> 17], 1);
    srt[gbase + pos] = (int)(e & 0x1FFFFu);
  }
}

// ------------- aggregation (bf16, START-semantics offs), 8-deep unroll ------
// (proven 63.5µs wave-per-node structure)
__global__ void k_gather_bf(const unsigned int* __restrict__ X1,
                            const int* __restrict__ deg, const int* __restrict__ offs,
                            const int* __restrict__ srt, unsigned int* __restrict__ h0) {
  int node = blockIdx.x * 4 + (threadIdx.x >> 6);
  int lane = threadIdx.x & 63;
  unsigned u = X1[(size_t)node * 64 + lane];
  float hx = bflo(u), hy = bfhi(u);
  int e = offs[node];
  int end = e + deg[node];
  for (; e + 8 <= end; e += 8) {
    int s0 = srt[e],     s1 = srt[e + 1], s2 = srt[e + 2], s3 = srt[e + 3];
    int s4 = srt[e + 4], s5 = srt[e + 5], s6 = srt[e + 6], s7 = srt[e + 7];
    unsigned u0 = X1[(size_t)s0 * 64 + lane];
    unsigned u1 = X1[(size_t)s1 * 64 + lane];
    unsigned u2 = X1[(size_t)s2 * 64 + lane];
    unsigned u3 = X1[(size_t)s3 * 64 + lane];
    unsigned u4 = X1[(size_t)s4 * 64 + lane];
    unsigned u5 = X1[(size_t)s5 * 64 + lane];
    unsigned u6 = X1[(size_t)s6 * 64 + lane];
    unsigned u7 = X1[(size_t)s7 * 64 + lane];
    hx += bflo(u0); hy += bfhi(u0);
    hx += bflo(u1); hy += bfhi(u1);
    hx += bflo(u2); hy += bfhi(u2);
    hx += bflo(u3); hy += bfhi(u3);
    hx += bflo(u4); hy += bfhi(u4);
    hx += bflo(u5); hy += bfhi(u5);
    hx += bflo(u6); hy += bfhi(u6);
    hx += bflo(u7); hy += bfhi(u7);
  }
  for (; e + 2 <= end; e += 2) {
    unsigned u0 = X1[(size_t)srt[e] * 64 + lane];
    unsigned u1 = X1[(size_t)srt[e + 1] * 64 + lane];
    hx += bflo(u0); hy += bfhi(u0);
    hx += bflo(u1); hy += bfhi(u1);
  }
  for (; e < end; ++e) {
    unsigned u0 = X1[(size_t)srt[e] * 64 + lane];
    hx += bflo(u0); hy += bfhi(u0);
  }
  h0[(size_t)node * 64 + lane] = ((unsigned)f2bf(hy) << 16) | f2bf(hx);
}

// ============ k_mlp2: BR=128, 8 waves (wave owns 16 rows), 2 blocks/CU ======
// (round-7/10 proven, row-major h0) W1 in LDS; restage W2 after GEMM1.
#define BR2 128

__launch_bounds__(512, 4)
__global__ void k_mlp2(const unsigned short* __restrict__ h0,
                       const unsigned short* __restrict__ Wimg,
                       const float* __restrict__ b1v, const float* __restrict__ b2v,
                       float* __restrict__ out) {
  __shared__ __attribute__((aligned(16))) unsigned short lW[128 * PADK];
  __shared__ __attribute__((aligned(16))) unsigned short lH[BR2 * PADK];

  const int t = threadIdx.x;
  const int wave = t >> 6, lane = t & 63;
  const int lr = lane & 15, lg = lane >> 4;
  const int row0 = blockIdx.x * BR2;
  const int wrow = row0 + wave * 16;

  const uint4* wi = (const uint4*)Wimg;
  uint4* lw = (uint4*)lW;

  // stage W1 image (2176 uint4)
  for (int i = t; i < 2176; i += 512) lw[i] = wi[i];

  // A fragments from global bf16 h0
  bf16x8 a[4];
#pragma unroll
  for (int kb = 0; kb < 4; ++kb) {
    int r = wrow + lr;
    if (r >= N_NODES) r = N_NODES - 1;          // clamp; result unused
    a[kb] = __builtin_bit_cast(bf16x8,
        *(const short8*)(h0 + (size_t)r * D + kb * 32 + lg * 8));
  }

  f32x4 acc[8];
#pragma unroll
  for (int nc = 0; nc < 8; ++nc) {
    float bb = b1v[nc * 16 + lr];
    acc[nc] = (f32x4){bb, bb, bb, bb};
  }

  __syncthreads();   // W1 staged

  // GEMM1
#pragma unroll
  for (int nc = 0; nc < 8; ++nc) {
#pragma unroll
    for (int kb = 0; kb < 4; ++kb) {
      bf16x8 b = *(const bf16x8*)&lW[(nc * 16 + lr) * PADK + kb * 32 + lg * 8];
      acc[nc] = __builtin_amdgcn_mfma_f32_16x16x32_bf16(a[kb], b, acc[nc], 0, 0, 0);
    }
  }

  __syncthreads();   // everyone done reading W1

  // restage W2
  {
    const uint4* wi2 = (const uint4*)Wimg + 2176;
    for (int i = t; i < 2176; i += 512) lw[i] = wi2[i];
  }

  // ReLU -> h1 into own stripe (intra-wave dependency only)
#pragma unroll
  for (int nc = 0; nc < 8; ++nc) {
#pragma unroll
    for (int r = 0; r < 4; ++r) {
      float v = acc[nc][r];
      v = v > 0.f ? v : 0.f;
      lH[(wave * 16 + lg * 4 + r) * PADK + nc * 16 + lr] = f2bf(v);
    }
  }

  __syncthreads();   // W2 staged

  bf16x8 a2[4];
#pragma unroll
  for (int kb = 0; kb < 4; ++kb)
    a2[kb] = *(const bf16x8*)&lH[(wave * 16 + lr) * PADK + kb * 32 + lg * 8];

#pragma unroll
  for (int nc = 0; nc < 8; ++nc) {
    float bb = b2v[nc * 16 + lr];
    acc[nc] = (f32x4){bb, bb, bb, bb};
  }

  // GEMM2
#pragma unroll
  for (int nc = 0; nc < 8; ++nc) {
#pragma unroll
    for (int kb = 0; kb < 4; ++kb) {
      bf16x8 b = *(const bf16x8*)&lW[(nc * 16 + lr) * PADK + kb * 32 + lg * 8];
      acc[nc] = __builtin_amdgcn_mfma_f32_16x16x32_bf16(a2[kb], b, acc[nc], 0, 0, 0);
    }
  }

  // store f32
#pragma unroll
  for (int nc = 0; nc < 8; ++nc) {
#pragma unroll
    for (int r = 0; r < 4; ++r) {
      int row = wrow + lg * 4 + r;
      if (row < N_NODES) out[(size_t)row * D + nc * 16 + lr] = acc[nc][r];
    }
  }
}

// ================= old CSR build (fallback path, end-semantics offs) ========

__global__ void k_hist(const int* __restrict__ dst, int* __restrict__ deg) {
  int i = blockIdx.x * 256 + threadIdx.x;
  if (i < N_EDGES) atomicAdd(&deg[dst[i]], 1);
}

__global__ void k_scan1(const int* __restrict__ deg, int* __restrict__ offs,
                        int* __restrict__ bsum) {
  __shared__ int s[1024];
  int t = threadIdx.x;
  int i = blockIdx.x * 1024 + t;
  int v = (i < N_NODES) ? deg[i] : 0;
  s[t] = v;
  __syncthreads();
  for (int d = 1; d < 1024; d <<= 1) {
    int x = (t >= d) ? s[t - d] : 0;
    __syncthreads();
    s[t] += x;
    __syncthreads();
  }
  if (i < N_NODES) offs[i] = s[t] - v;
  if (t == 1023) bsum[blockIdx.x] = s[t];
}

__global__ void k_scan2(int* __restrict__ bsum) {
  __shared__ int s[128];
  int t = threadIdx.x;
  int v = (t < 98) ? bsum[t] : 0;
  s[t] = v;
  __syncthreads();
  for (int d = 1; d < 128; d <<= 1) {
    int x = (t >= d) ? s[t - d] : 0;
    __syncthreads();
    s[t] += x;
    __syncthreads();
  }
  if (t < 98) bsum[t] = s[t] - v;
}

__global__ void k_scan3(int* __restrict__ offs, const int* __restrict__ bsum) {
  int i = blockIdx.x * 1024 + threadIdx.x;
  if (i < N_NODES) offs[i] += bsum[blockIdx.x];
}

__global__ void k_bucket(const int* __restrict__ src, const int* __restrict__ dst,
                         int* __restrict__ offs, int* __restrict__ srt) {
  int i = blockIdx.x * 256 + threadIdx.x;
  if (i < N_EDGES) {
    int pos = atomicAdd(&offs[dst[i]], 1);
    srt[pos] = src[i];
  }
}

__global__ void k_gather(const float* __restrict__ X, const int* __restrict__ deg,
                         const int* __restrict__ offs, const int* __restrict__ srt,
                         float* __restrict__ out) {
  int node = blockIdx.x * 4 + (threadIdx.x >> 6);
  int lane = threadIdx.x & 63;
  const float2* X2 = (const float2*)X;
  float2 h = X2[(size_t)node * 64 + lane];
  int end = offs[node];
  int dg = deg[node];
  for (int e = end - dg; e < end; ++e) {
    int s = srt[e];
    float2 x = X2[(size_t)s * 64 + lane];
    h.x += x.x; h.y += x.y;
  }
  ((float2*)out)[(size_t)node * 64 + lane] = h;
}

#define BR 256

__launch_bounds__(512, 1)
__global__ void k_mlp(const float* __restrict__ h0,
                      const float* __restrict__ W1, const float* __restrict__ b1,
                      const float* __restrict__ W2, const float* __restrict__ b2,
                      float* __restrict__ out) {
  __shared__ __attribute__((aligned(16))) unsigned short lW[2 * 128 * PADK];
  __shared__ __attribute__((aligned(16))) unsigned short lH[BR * PADK];

  const int t = threadIdx.x;
  const int wave = t >> 6, lane = t & 63;
  const int lr = lane & 15, lg = lane >> 4;
  const int row0 = blockIdx.x * BR;
  const int wrow = row0 + wave * 32;

  for (int i = t; i < 128 * 128; i += 512) {
    int k = i >> 7, n = i & 127;
    lW[n * PADK + k] = f2bf(W1[i]);
    lW[128 * PADK + n * PADK + k] = f2bf(W2[i]);
  }

  bf16x8 a[2][4];
#pragma unroll
  for (int tr = 0; tr < 2; ++tr) {
#pragma unroll
    for (int kb = 0; kb < 4; ++kb) {
      int r = wrow + tr * 16 + lr;
      if (r >= N_NODES) r = N_NODES - 1;
      const float4* p = (const float4*)(h0 + (size_t)r * D + kb * 32 + lg * 8);
      float4 f0 = p[0], f1 = p[1];
      short8 s;
      s[0] = f2bf(f0.x); s[1] = f2bf(f0.y); s[2] = f2bf(f0.z); s[3] = f2bf(f0.w);
      s[4] = f2bf(f1.x); s[5] = f2bf(f1.y); s[6] = f2bf(f1.z); s[7] = f2bf(f1.w);
      a[tr][kb] = __builtin_bit_cast(bf16x8, s);
    }
  }

  f32x4 acc[2][8];
#pragma unroll
  for (int nc = 0; nc < 8; ++nc) {
    float bb = b1[nc * 16 + lr];
#pragma unroll
    for (int tr = 0; tr < 2; ++tr) acc[tr][nc] = (f32x4){bb, bb, bb, bb};
  }

  __syncthreads();

#pragma unroll
  for (int nc = 0; nc < 8; ++nc) {
#pragma unroll
    for (int kb = 0; kb < 4; ++kb) {
      bf16x8 b = *(const bf16x8*)&lW[(nc * 16 + lr) * PADK + kb * 32 + lg * 8];
#pragma unroll
      for (int tr = 0; tr < 2; ++tr)
        acc[tr][nc] = __builtin_amdgcn_mfma_f32_16x16x32_bf16(a[tr][kb], b, acc[tr][nc], 0, 0, 0);
    }
  }

#pragma unroll
  for (int tr = 0; tr < 2; ++tr) {
#pragma unroll
    for (int nc = 0; nc < 8; ++nc) {
#pragma unroll
      for (int r = 0; r < 4; ++r) {
        float v = acc[tr][nc][r];
        v = v > 0.f ? v : 0.f;
        int lrow = wave * 32 + tr * 16 + lg * 4 + r;
        lH[lrow * PADK + nc * 16 + lr] = f2bf(v);
      }
    }
  }

  __syncthreads();

  bf16x8 a2[2][4];
#pragma unroll
  for (int tr = 0; tr < 2; ++tr) {
#pragma unroll
    for (int kb = 0; kb < 4; ++kb)
      a2[tr][kb] = *(const bf16x8*)&lH[(wave * 32 + tr * 16 + lr) * PADK + kb * 32 + lg * 8];
  }

#pragma unroll
  for (int nc = 0; nc < 8; ++nc) {
    float bb = b2[nc * 16 + lr];
#pragma unroll
    for (int tr = 0; tr < 2; ++tr) acc[tr][nc] = (f32x4){bb, bb, bb, bb};
  }

#pragma unroll
  for (int nc = 0; nc < 8; ++nc) {
#pragma unroll
    for (int kb = 0; kb < 4; ++kb) {
      bf16x8 b = *(const bf16x8*)&lW[128 * PADK + (nc * 16 + lr) * PADK + kb * 32 + lg * 8];
#pragma unroll
      for (int tr = 0; tr < 2; ++tr)
        acc[tr][nc] = __builtin_amdgcn_mfma_f32_16x16x32_bf16(a2[tr][kb], b, acc[tr][nc], 0, 0, 0);
    }
  }

#pragma unroll
  for (int tr = 0; tr < 2; ++tr) {
#pragma unroll
    for (int nc = 0; nc < 8; ++nc) {
#pragma unroll
      for (int r = 0; r < 4; ++r) {
        int row = wrow + tr * 16 + lg * 4 + r;
        if (row < N_NODES) out[(size_t)row * D + nc * 16 + lr] = acc[tr][nc][r];
      }
    }
  }
}

extern "C" void kernel_launch(void* const* d_in, const int* in_sizes, int n_in,
                              void* d_out, int out_size, void* d_ws, size_t ws_size,
                              hipStream_t stream) {
  const float* X  = (const float*)d_in[0];
  const float* W1 = (const float*)d_in[1];
  const float* b1 = (const float*)d_in[2];
  const float* W2 = (const float*)d_in[3];
  const float* b2 = (const float*)d_in[4];
  const int* esrc = (const int*)d_in[5];
  const int* edst = (const int*)d_in[6];
  float* out = (float*)d_out;

  char* ws = (char*)d_ws;
  // round-10 proven layout (row-major Xb/h0b)
  int* deg      = (int*)(ws);                          // 400,000 B
  int* offs     = (int*)(ws + 400000);                 // 400,000 B
  int* srt      = (int*)(ws + 800000);                 // 6,400,000 B -> 7,200,000
  unsigned short* Xb  = (unsigned short*)(ws + 7200000);   // 25.6 MB -> 32,800,000
  unsigned short* h0b = (unsigned short*)(ws + 32800000);  // 25.6 MB -> 58,400,000
  // aliases inside h0b (dead before gather writes h0b):
  unsigned* binbuf = (unsigned*)(ws + 32800000);           // 6,422,528 B
  int* cntmatT   = (int*)(ws + 32800000 + 6422528);        // 153,664 B
  int* startmatT = (int*)(ws + 32800000 + 6422528 + 153664);
  unsigned short* Wimg = (unsigned short*)(ws + 58400000); // 69,632 B
  const size_t NEED = 58469632;

  if (ws_size >= NEED) {
    k_head<<<RBLK + HEAD_W_BLOCKS + HEAD_CVT_BLOCKS, 512, 0, stream>>>(
        esrc, edst, binbuf, cntmatT, startmatT, X, Xb, W1, W2, Wimg);
    k_sort<<<NBINS, 512, 0, stream>>>(binbuf, cntmatT, startmatT, srt, deg, offs);
    k_gather_bf<<<N_NODES / 4, 256, 0, stream>>>((const unsigned*)Xb, deg, offs, srt,
                                                 (unsigned*)h0b);
    k_mlp2<<<(N_NODES + BR2 - 1) / BR2, 512, 0, stream>>>(h0b, Wimg, b1, b2, out);
  } else {
    // fallback: proven round-1 pipeline (f32 gather, END-semantics offs)
    int* bsum = (int*)(ws + 800000);
    int* srtF = (int*)(ws + 802048);
    hipMemsetAsync(deg, 0, N_NODES * sizeof(int), stream);
    k_hist  <<<N_EDGES / 256, 256, 0, stream>>>(edst, deg);
    k_scan1 <<<98, 1024, 0, stream>>>(deg, offs, bsum);
    k_scan2 <<<1, 128, 0, stream>>>(bsum);
    k_scan3 <<<98, 1024, 0, stream>>>(offs, bsum);
    k_bucket<<<N_EDGES / 256, 256, 0, stream>>>(esrc, edst, offs, srtF);
    k_gather<<<N_NODES / 4, 256, 0, stream>>>(X, deg, offs, srtF, out);
    k_mlp   <<<(N_NODES + BR - 1) / BR, 512, 0, stream>>>(out, W1, b1, W2, b2, out);
  }
}

// Round 14
// 129.885 us; speedup vs baseline: 1.3087x; 1.0351x over previous
//
#include <hip/hip_runtime.h>
#include <hip/hip_bf16.h>

#define N_NODES 100000
#define N_EDGES 1600000
#define D 128

#define NBINS 196       // ceil(100000 / 512) node bins
#define BINSHIFT 9      // 512 nodes per bin
#define EPB 8192        // edges per region (k_head bin block)
#define RBLK 196        // edge regions = ceil(N_EDGES / EPB)
#define EBUF_CAP 8960   // LDS staging cap per bin (mean 8163, ~8.8 sigma)

// k_head block layout: [0,196) bin, [196,204) W image, [204,3329) X cvt
#define HEAD_W_BLOCKS 8
#define HEAD_CVT_BLOCKS 3125   // 100000*128 / (512*8)

#define PADK 136

typedef __bf16 bf16x8 __attribute__((ext_vector_type(8)));
typedef short short8 __attribute__((ext_vector_type(8)));
typedef float f32x4 __attribute__((ext_vector_type(4)));

__device__ __forceinline__ unsigned short f2bf(float f) {
  union { float f; unsigned u; } c; c.f = f;
  unsigned u = c.u;
  u += 0x7FFFu + ((u >> 16) & 1u);   // round-to-nearest-even
  return (unsigned short)(u >> 16);
}
__device__ __forceinline__ float bflo(unsigned u) {
  union { unsigned u; float f; } c; c.u = u << 16; return c.f;
}
__device__ __forceinline__ float bfhi(unsigned u) {
  union { unsigned u; float f; } c; c.u = u & 0xFFFF0000u; return c.f;
}

// ============ k_head: fused edge binning (FIRST) + W image + X cvt ==========
// Bin blocks: LDS counting sort by coarse bin, dense 32KB stream-out into a
// private region; emits [bin][region] count/start matrices. Zero global
// atomics, zero memset. Bin blocks overlap with cvt blocks -> head makespan
// ~= max(bin, cvt), not sum. (round-11 proven verbatim)
__launch_bounds__(512)
__global__ void k_head(const int* __restrict__ esrc, const int* __restrict__ edst,
                       unsigned* __restrict__ binbuf, int* __restrict__ cntmatT,
                       int* __restrict__ startmatT,
                       const float* __restrict__ X, unsigned short* __restrict__ Xb,
                       const float* __restrict__ W1, const float* __restrict__ W2,
                       unsigned short* __restrict__ Wimg) {
  const int b = blockIdx.x, t = threadIdx.x;

  if (b < RBLK) {
    __shared__ unsigned lbuf[EPB];       // 32 KB
    __shared__ int cnt[NBINS];
    __shared__ int base[NBINS];
    __shared__ int cur[NBINS];
    __shared__ int scanb[256];
    const int e0 = b * EPB;
    const int ne = min(EPB, N_EDGES - e0);

    for (int i = t; i < NBINS; i += 512) { cnt[i] = 0; cur[i] = 0; }
    __syncthreads();
    for (int i = t; i < ne; i += 512)
      atomicAdd(&cnt[edst[e0 + i] >> BINSHIFT], 1);
    __syncthreads();
    if (t < 256) scanb[t] = (t < NBINS) ? cnt[t] : 0;
    __syncthreads();
    for (int d = 1; d < 256; d <<= 1) {
      int x = 0;
      if (t < 256 && t >= d) x = scanb[t - d];
      __syncthreads();
      if (t < 256) scanb[t] += x;
      __syncthreads();
    }
    if (t < NBINS) base[t] = scanb[t] - cnt[t];
    __syncthreads();
    for (int i = t; i < ne; i += 512) {
      int d = edst[e0 + i];
      int s = esrc[e0 + i];
      int bi = d >> BINSHIFT;
      int pos = base[bi] + atomicAdd(&cur[bi], 1);
      lbuf[pos] = ((unsigned)(d & 511) << 17) | (unsigned)s;
    }
    __syncthreads();
    // dense stream-out (garbage tail never referenced via counts)
    uint4* dst4 = (uint4*)(binbuf + (size_t)b * EPB);
    const uint4* src4 = (const uint4*)lbuf;
    for (int i = t; i < EPB / 4; i += 512) dst4[i] = src4[i];
    if (t < NBINS) {
      cntmatT[t * RBLK + b] = cnt[t];     // [bin][region]
      startmatT[t * RBLK + b] = base[t];
    }
    return;
  }
  if (b < RBLK + HEAD_W_BLOCKS) {
    int bb = b - RBLK;
    const float* W = (bb & 4) ? W2 : W1;
    unsigned short* img = Wimg + ((bb & 4) ? 128 * PADK : 0);
    int k0 = (bb & 3) * 32;
#pragma unroll
    for (int it = 0; it < 8; ++it) {
      int idx = it * 512 + t;                 // 4096 entries: 32 k x 128 n
      int k = k0 + (idx >> 7), n = idx & 127;
      img[n * PADK + k] = f2bf(W[k * 128 + n]);
    }
    return;
  }
  // ---- X f32 -> bf16 ----
  size_t i = ((size_t)(b - RBLK - HEAD_W_BLOCKS) * 512 + t) * 8;
  const float4* p = (const float4*)(X + i);
  float4 a = p[0], c = p[1];
  short8 s;
  s[0] = f2bf(a.x); s[1] = f2bf(a.y); s[2] = f2bf(a.z); s[3] = f2bf(a.w);
  s[4] = f2bf(c.x); s[5] = f2bf(c.y); s[6] = f2bf(c.z); s[7] = f2bf(c.w);
  *(short8*)(Xb + i) = s;
}

// ============ k_sortgather: per-bin sort (LDS-resident) + gather ============
// Block b: gather its bin's edges from the 196 region chunks into ebuf,
// count/scan/scatter to per-node-sorted ebuf2 (src only), then 16 waves
// gather 32 nodes each (8-deep unrolled row reads) and write h0 bf16.
// No srt/deg/offs global round-trip at all. (round-11 proven verbatim)
__launch_bounds__(1024)
__global__ void k_sortgather(const unsigned* __restrict__ binbuf,
                             const int* __restrict__ cntmatT,
                             const int* __restrict__ startmatT,
                             const unsigned* __restrict__ X1,
                             unsigned* __restrict__ h0) {
  __shared__ unsigned ebuf[EBUF_CAP];    // 35 KB
  __shared__ unsigned ebuf2[EBUF_CAP];   // 35 KB
  __shared__ int hist[512];
  __shared__ int scn[512];
  __shared__ int nstart[512];
  __shared__ int ncnt[512];
  __shared__ int rcnt[RBLK];
  __shared__ int roff[RBLK];
  __shared__ int eoff[RBLK];
  __shared__ int s_total;

  const int b = blockIdx.x, t = threadIdx.x;
  const int n0 = b << BINSHIFT;
  const int wv = t >> 6, ln = t & 63;

  // this bin's per-region counts/starts (coalesced 784B rows)
  for (int r = t; r < RBLK; r += 1024) {
    rcnt[r] = cntmatT[b * RBLK + r];
    roff[r] = startmatT[b * RBLK + r];
  }
  __syncthreads();

  // eoff = exclusive scan of rcnt; total = edges in this bin
  if (t < 256) scn[t] = (t < RBLK) ? rcnt[t] : 0;
  __syncthreads();
  for (int d = 1; d < 256; d <<= 1) {
    int x = 0;
    if (t < 256 && t >= d) x = scn[t - d];
    __syncthreads();
    if (t < 256) scn[t] += x;
    __syncthreads();
  }
  if (t < RBLK) eoff[t] = scn[t] - rcnt[t];
  if (t == RBLK - 1) s_total = scn[t];
  __syncthreads();
  const int mytotal = s_total;

  // gather this bin's edges from all regions into LDS (wave wv: r = wv mod 16)
  for (int r = wv; r < RBLK; r += 16) {
    const unsigned* src = binbuf + (size_t)r * EPB + roff[r];
    int c = rcnt[r], o = eoff[r];
    for (int i = ln; i < c; i += 64) ebuf[o + i] = src[i];
  }
  if (t < 512) hist[t] = 0;
  __syncthreads();

  // per-node counts
  for (int i = t; i < mytotal; i += 1024)
    atomicAdd(&hist[ebuf[i] >> 17], 1);
  __syncthreads();
  int v = (t < 512) ? hist[t] : 0;
  if (t < 512) scn[t] = v;
  __syncthreads();
  for (int d = 1; d < 512; d <<= 1) {
    int x = 0;
    if (t < 512 && t >= d) x = scn[t - d];
    __syncthreads();
    if (t < 512) scn[t] += x;
    __syncthreads();
  }
  if (t < 512) {
    nstart[t] = scn[t] - v;
    ncnt[t] = v;
    hist[t] = scn[t] - v;   // write cursor
  }
  __syncthreads();
  // scatter to per-node-sorted order; keep only src (17 bits)
  for (int i = t; i < mytotal; i += 1024) {
    unsigned e = ebuf[i];
    int pos = atomicAdd(&hist[e >> 17], 1);
    ebuf2[pos] = e & 0x1FFFFu;
  }
  __syncthreads();

  // ---- gather phase: wave wv owns local nodes [wv*32, wv*32+32) ----
  for (int j = 0; j < 32; ++j) {
    int li = wv * 32 + j;
    int node = n0 + li;
    if (node >= N_NODES) break;
    unsigned u = X1[(size_t)node * 64 + ln];
    float hx = bflo(u), hy = bfhi(u);
    int e = nstart[li];
    int end = e + ncnt[li];
    for (; e + 8 <= end; e += 8) {
      int s0 = ebuf2[e],     s1 = ebuf2[e + 1], s2 = ebuf2[e + 2], s3 = ebuf2[e + 3];
      int s4 = ebuf2[e + 4], s5 = ebuf2[e + 5], s6 = ebuf2[e + 6], s7 = ebuf2[e + 7];
      unsigned u0 = X1[(size_t)s0 * 64 + ln];
      unsigned u1 = X1[(size_t)s1 * 64 + ln];
      unsigned u2 = X1[(size_t)s2 * 64 + ln];
      unsigned u3 = X1[(size_t)s3 * 64 + ln];
      unsigned u4 = X1[(size_t)s4 * 64 + ln];
      unsigned u5 = X1[(size_t)s5 * 64 + ln];
      unsigned u6 = X1[(size_t)s6 * 64 + ln];
      unsigned u7 = X1[(size_t)s7 * 64 + ln];
      hx += bflo(u0); hy += bfhi(u0);
      hx += bflo(u1); hy += bfhi(u1);
      hx += bflo(u2); hy += bfhi(u2);
      hx += bflo(u3); hy += bfhi(u3);
      hx += bflo(u4); hy += bfhi(u4);
      hx += bflo(u5); hy += bfhi(u5);
      hx += bflo(u6); hy += bfhi(u6);
      hx += bflo(u7); hy += bfhi(u7);
    }
    for (; e + 2 <= end; e += 2) {
      unsigned u0 = X1[(size_t)ebuf2[e] * 64 + ln];
      unsigned u1 = X1[(size_t)ebuf2[e + 1] * 64 + ln];
      hx += bflo(u0); hy += bfhi(u0);
      hx += bflo(u1); hy += bfhi(u1);
    }
    for (; e < end; ++e) {
      unsigned u0 = X1[(size_t)ebuf2[e] * 64 + ln];
      hx += bflo(u0); hy += bfhi(u0);
    }
    h0[(size_t)node * 64 + ln] = ((unsigned)f2bf(hy) << 16) | f2bf(hx);
  }
}

// ============ k_mlp2: BR=128, 8 waves (wave owns 16 rows), 2 blocks/CU ======
// (round-7/10/11 proven) W1 staged in LDS; restage W2 after GEMM1.
#define BR2 128

__launch_bounds__(512, 4)
__global__ void k_mlp2(const unsigned short* __restrict__ h0,
                       const unsigned short* __restrict__ Wimg,
                       const float* __restrict__ b1v, const float* __restrict__ b2v,
                       float* __restrict__ out) {
  __shared__ __attribute__((aligned(16))) unsigned short lW[128 * PADK];
  __shared__ __attribute__((aligned(16))) unsigned short lH[BR2 * PADK];

  const int t = threadIdx.x;
  const int wave = t >> 6, lane = t & 63;
  const int lr = lane & 15, lg = lane >> 4;
  const int row0 = blockIdx.x * BR2;
  const int wrow = row0 + wave * 16;

  const uint4* wi = (const uint4*)Wimg;
  uint4* lw = (uint4*)lW;

  // stage W1 image (2176 uint4)
  for (int i = t; i < 2176; i += 512) lw[i] = wi[i];

  // A fragments from global bf16 h0
  bf16x8 a[4];
#pragma unroll
  for (int kb = 0; kb < 4; ++kb) {
    int r = wrow + lr;
    if (r >= N_NODES) r = N_NODES - 1;          // clamp; result unused
    a[kb] = __builtin_bit_cast(bf16x8,
        *(const short8*)(h0 + (size_t)r * D + kb * 32 + lg * 8));
  }

  f32x4 acc[8];
#pragma unroll
  for (int nc = 0; nc < 8; ++nc) {
    float bb = b1v[nc * 16 + lr];
    acc[nc] = (f32x4){bb, bb, bb, bb};
  }

  __syncthreads();   // W1 staged

  // GEMM1
#pragma unroll
  for (int nc = 0; nc < 8; ++nc) {
#pragma unroll
    for (int kb = 0; kb < 4; ++kb) {
      bf16x8 b = *(const bf16x8*)&lW[(nc * 16 + lr) * PADK + kb * 32 + lg * 8];
      acc[nc] = __builtin_amdgcn_mfma_f32_16x16x32_bf16(a[kb], b, acc[nc], 0, 0, 0);
    }
  }

  __syncthreads();   // everyone done reading W1

  // restage W2
  {
    const uint4* wi2 = (const uint4*)Wimg + 2176;
    for (int i = t; i < 2176; i += 512) lw[i] = wi2[i];
  }

  // ReLU -> h1 into own stripe (intra-wave dependency only)
#pragma unroll
  for (int nc = 0; nc < 8; ++nc) {
#pragma unroll
    for (int r = 0; r < 4; ++r) {
      float v = acc[nc][r];
      v = v > 0.f ? v : 0.f;
      lH[(wave * 16 + lg * 4 + r) * PADK + nc * 16 + lr] = f2bf(v);
    }
  }

  __syncthreads();   // W2 staged

  bf16x8 a2[4];
#pragma unroll
  for (int kb = 0; kb < 4; ++kb)
    a2[kb] = *(const bf16x8*)&lH[(wave * 16 + lr) * PADK + kb * 32 + lg * 8];

#pragma unroll
  for (int nc = 0; nc < 8; ++nc) {
    float bb = b2v[nc * 16 + lr];
    acc[nc] = (f32x4){bb, bb, bb, bb};
  }

  // GEMM2
#pragma unroll
  for (int nc = 0; nc < 8; ++nc) {
#pragma unroll
    for (int kb = 0; kb < 4; ++kb) {
      bf16x8 b = *(const bf16x8*)&lW[(nc * 16 + lr) * PADK + kb * 32 + lg * 8];
      acc[nc] = __builtin_amdgcn_mfma_f32_16x16x32_bf16(a2[kb], b, acc[nc], 0, 0, 0);
    }
  }

  // store f32
#pragma unroll
  for (int nc = 0; nc < 8; ++nc) {
#pragma unroll
    for (int r = 0; r < 4; ++r) {
      int row = wrow + lg * 4 + r;
      if (row < N_NODES) out[(size_t)row * D + nc * 16 + lr] = acc[nc][r];
    }
  }
}

// ================= old CSR build (fallback path, end-semantics offs) ========

__global__ void k_hist(const int* __restrict__ dst, int* __restrict__ deg) {
  int i = blockIdx.x * 256 + threadIdx.x;
  if (i < N_EDGES) atomicAdd(&deg[dst[i]], 1);
}

__global__ void k_scan1(const int* __restrict__ deg, int* __restrict__ offs,
                        int* __restrict__ bsum) {
  __shared__ int s[1024];
  int t = threadIdx.x;
  int i = blockIdx.x * 1024 + t;
  int v = (i < N_NODES) ? deg[i] : 0;
  s[t] = v;
  __syncthreads();
  for (int d = 1; d < 1024; d <<= 1) {
    int x = (t >= d) ? s[t - d] : 0;
    __syncthreads();
    s[t] += x;
    __syncthreads();
  }
  if (i < N_NODES) offs[i] = s[t] - v;
  if (t == 1023) bsum[blockIdx.x] = s[t];
}

__global__ void k_scan2(int* __restrict__ bsum) {
  __shared__ int s[128];
  int t = threadIdx.x;
  int v = (t < 98) ? bsum[t] : 0;
  s[t] = v;
  __syncthreads();
  for (int d = 1; d < 128; d <<= 1) {
    int x = (t >= d) ? s[t - d] : 0;
    __syncthreads();
    s[t] += x;
    __syncthreads();
  }
  if (t < 98) bsum[t] = s[t] - v;
}

__global__ void k_scan3(int* __restrict__ offs, const int* __restrict__ bsum) {
  int i = blockIdx.x * 1024 + threadIdx.x;
  if (i < N_NODES) offs[i] += bsum[blockIdx.x];
}

__global__ void k_bucket(const int* __restrict__ src, const int* __restrict__ dst,
                         int* __restrict__ offs, int* __restrict__ srt) {
  int i = blockIdx.x * 256 + threadIdx.x;
  if (i < N_EDGES) {
    int pos = atomicAdd(&offs[dst[i]], 1);
    srt[pos] = src[i];
  }
}

// ------------- f32 fallback gather (END-semantics offs) -------------
__global__ void k_gather(const float* __restrict__ X, const int* __restrict__ deg,
                         const int* __restrict__ offs, const int* __restrict__ srt,
                         float* __restrict__ out) {
  int node = blockIdx.x * 4 + (threadIdx.x >> 6);
  int lane = threadIdx.x & 63;
  const float2* X2 = (const float2*)X;
  float2 h = X2[(size_t)node * 64 + lane];
  int end = offs[node];
  int dg = deg[node];
  for (int e = end - dg; e < end; ++e) {
    int s = srt[e];
    float2 x = X2[(size_t)s * 64 + lane];
    h.x += x.x; h.y += x.y;
  }
  ((float2*)out)[(size_t)node * 64 + lane] = h;
}

// ------------- fallback fused MLP (f32 h0 in d_out, in-place) -------------
#define BR 256

__launch_bounds__(512, 1)
__global__ void k_mlp(const float* __restrict__ h0,
                      const float* __restrict__ W1, const float* __restrict__ b1,
                      const float* __restrict__ W2, const float* __restrict__ b2,
                      float* __restrict__ out) {
  __shared__ __attribute__((aligned(16))) unsigned short lW[2 * 128 * PADK];
  __shared__ __attribute__((aligned(16))) unsigned short lH[BR * PADK];

  const int t = threadIdx.x;
  const int wave = t >> 6, lane = t & 63;
  const int lr = lane & 15, lg = lane >> 4;
  const int row0 = blockIdx.x * BR;
  const int wrow = row0 + wave * 32;

  for (int i = t; i < 128 * 128; i += 512) {
    int k = i >> 7, n = i & 127;
    lW[n * PADK + k] = f2bf(W1[i]);
    lW[128 * PADK + n * PADK + k] = f2bf(W2[i]);
  }

  bf16x8 a[2][4];
#pragma unroll
  for (int tr = 0; tr < 2; ++tr) {
#pragma unroll
    for (int kb = 0; kb < 4; ++kb) {
      int r = wrow + tr * 16 + lr;
      if (r >= N_NODES) r = N_NODES - 1;
      const float4* p = (const float4*)(h0 + (size_t)r * D + kb * 32 + lg * 8);
      float4 f0 = p[0], f1 = p[1];
      short8 s;
      s[0] = f2bf(f0.x); s[1] = f2bf(f0.y); s[2] = f2bf(f0.z); s[3] = f2bf(f0.w);
      s[4] = f2bf(f1.x); s[5] = f2bf(f1.y); s[6] = f2bf(f1.z); s[7] = f2bf(f1.w);
      a[tr][kb] = __builtin_bit_cast(bf16x8, s);
    }
  }

  f32x4 acc[2][8];
#pragma unroll
  for (int nc = 0; nc < 8; ++nc) {
    float bb = b1[nc * 16 + lr];
#pragma unroll
    for (int tr = 0; tr < 2; ++tr) acc[tr][nc] = (f32x4){bb, bb, bb, bb};
  }

  __syncthreads();

#pragma unroll
  for (int nc = 0; nc < 8; ++nc) {
#pragma unroll
    for (int kb = 0; kb < 4; ++kb) {
      bf16x8 b = *(const bf16x8*)&lW[(nc * 16 + lr) * PADK + kb * 32 + lg * 8];
#pragma unroll
      for (int tr = 0; tr < 2; ++tr)
        acc[tr][nc] = __builtin_amdgcn_mfma_f32_16x16x32_bf16(a[tr][kb], b, acc[tr][nc], 0, 0, 0);
    }
  }

#pragma unroll
  for (int tr = 0; tr < 2; ++tr) {
#pragma unroll
    for (int nc = 0; nc < 8; ++nc) {
#pragma unroll
      for (int r = 0; r < 4; ++r) {
        float v = acc[tr][nc][r];
        v = v > 0.f ? v : 0.f;
        int lrow = wave * 32 + tr * 16 + lg * 4 + r;
        lH[lrow * PADK + nc * 16 + lr] = f2bf(v);
      }
    }
  }

  __syncthreads();

  bf16x8 a2[2][4];
#pragma unroll
  for (int tr = 0; tr < 2; ++tr) {
#pragma unroll
    for (int kb = 0; kb < 4; ++kb)
      a2[tr][kb] = *(const bf16x8*)&lH[(wave * 32 + tr * 16 + lr) * PADK + kb * 32 + lg * 8];
  }

#pragma unroll
  for (int nc = 0; nc < 8; ++nc) {
    float bb = b2[nc * 16 + lr];
#pragma unroll
    for (int tr = 0; tr < 2; ++tr) acc[tr][nc] = (f32x4){bb, bb, bb, bb};
  }

#pragma unroll
  for (int nc = 0; nc < 8; ++nc) {
#pragma unroll
    for (int kb = 0; kb < 4; ++kb) {
      bf16x8 b = *(const bf16x8*)&lW[128 * PADK + (nc * 16 + lr) * PADK + kb * 32 + lg * 8];
#pragma unroll
      for (int tr = 0; tr < 2; ++tr)
        acc[tr][nc] = __builtin_amdgcn_mfma_f32_16x16x32_bf16(a2[tr][kb], b, acc[tr][nc], 0, 0, 0);
    }
  }

#pragma unroll
  for (int tr = 0; tr < 2; ++tr) {
#pragma unroll
    for (int nc = 0; nc < 8; ++nc) {
#pragma unroll
      for (int r = 0; r < 4; ++r) {
        int row = wrow + tr * 16 + lg * 4 + r;
        if (row < N_NODES) out[(size_t)row * D + nc * 16 + lr] = acc[tr][nc][r];
      }
    }
  }
}

extern "C" void kernel_launch(void* const* d_in, const int* in_sizes, int n_in,
                              void* d_out, int out_size, void* d_ws, size_t ws_size,
                              hipStream_t stream) {
  const float* X  = (const float*)d_in[0];
  const float* W1 = (const float*)d_in[1];
  const float* b1 = (const float*)d_in[2];
  const float* W2 = (const float*)d_in[3];
  const float* b2 = (const float*)d_in[4];
  const int* esrc = (const int*)d_in[5];
  const int* edst = (const int*)d_in[6];
  float* out = (float*)d_out;

  char* ws = (char*)d_ws;
  // primary layout — NO aliasing (sortgather reads binbuf & writes h0b in
  // the same kernel). NEED = 57,999,488 <= proven 58,471,680 budget.
  unsigned* binbuf = (unsigned*)(ws);                        // 6,422,528 B
  int* cntmatT   = (int*)(ws + 6422528);                     // 153,664 B
  int* startmatT = (int*)(ws + 6576192);                     // 153,664 B
  unsigned short* Xb  = (unsigned short*)(ws + 6729856);     // 25.6 MB
  unsigned short* h0b = (unsigned short*)(ws + 32329856);    // 25.6 MB
  unsigned short* Wimg = (unsigned short*)(ws + 57929856);   // 69,632 B
  const size_t NEED = 57999488;

  if (ws_size >= NEED) {
    k_head<<<RBLK + HEAD_W_BLOCKS + HEAD_CVT_BLOCKS, 512, 0, stream>>>(
        esrc, edst, binbuf, cntmatT, startmatT, X, Xb, W1, W2, Wimg);
    k_sortgather<<<NBINS, 1024, 0, stream>>>(binbuf, cntmatT, startmatT,
                                             (const unsigned*)Xb, (unsigned*)h0b);
    k_mlp2<<<(N_NODES + BR2 - 1) / BR2, 512, 0, stream>>>(h0b, Wimg, b1, b2, out);
  } else {
    // fallback: proven round-1 pipeline (f32 gather, END-semantics offs)
    int* deg  = (int*)(ws);                    // 400,000 B
    int* offs = (int*)(ws + 400000);           // 400,000 B
    int* bsum = (int*)(ws + 800000);           // 1 KB
    int* srtF = (int*)(ws + 802048);           // 6.4 MB
    hipMemsetAsync(deg, 0, N_NODES * sizeof(int), stream);
    k_hist  <<<N_EDGES / 256, 256, 0, stream>>>(edst, deg);
    k_scan1 <<<98, 1024, 0, stream>>>(deg, offs, bsum);
    k_scan2 <<<1, 128, 0, stream>>>(bsum);
    k_scan3 <<<98, 1024, 0, stream>>>(offs, bsum);
    k_bucket<<<N_EDGES / 256, 256, 0, stream>>>(esrc, edst, offs, srtF);
    k_gather<<<N_NODES / 4, 256, 0, stream>>>(X, deg, offs, srtF, out);
    k_mlp   <<<(N_NODES + BR - 1) / BR, 512, 0, stream>>>(out, W1, b1, W2, b2, out);
  }
}

// Round 15
// 118.317 us; speedup vs baseline: 1.4366x; 1.0978x over previous
//
#include <hip/hip_runtime.h>
#include <hip/hip_bf16.h>

#define N_NODES 100000
#define N_EDGES 1600000
#define D 128

#define BINSHIFT 8      // 256 nodes per bin
#define NB2 391         // ceil(100000 / 256) node bins
#define EPB 8192        // edges per region (k_head bin block)
#define RBLK 196        // edge regions = ceil(N_EDGES / EPB)
#define EBUF_CAP 4864   // LDS staging cap per bin (mean 4096, sigma 64 -> 12 sigma)

// k_head block layout: [0,196) bin, [196,204) W image, [204,3329) X cvt
#define HEAD_W_BLOCKS 8
#define HEAD_CVT_BLOCKS 3125   // 100000*128 / (512*8)

#define PADK 136

typedef __bf16 bf16x8 __attribute__((ext_vector_type(8)));
typedef short short8 __attribute__((ext_vector_type(8)));
typedef float f32x4 __attribute__((ext_vector_type(4)));

__device__ __forceinline__ unsigned short f2bf(float f) {
  union { float f; unsigned u; } c; c.f = f;
  unsigned u = c.u;
  u += 0x7FFFu + ((u >> 16) & 1u);   // round-to-nearest-even
  return (unsigned short)(u >> 16);
}
__device__ __forceinline__ float bflo(unsigned u) {
  union { unsigned u; float f; } c; c.u = u << 16; return c.f;
}
__device__ __forceinline__ float bfhi(unsigned u) {
  union { unsigned u; float f; } c; c.u = u & 0xFFFF0000u; return c.f;
}

// ============ k_head: fused edge binning (FIRST) + W image + X cvt ==========
// Bin blocks: LDS counting sort by 256-node bin, dense 32KB stream-out into a
// private region; emits [bin][region] count/start matrices (391 x 196).
// Zero global atomics, zero memset. Packing: (dst&255)<<17 | src.
__launch_bounds__(512)
__global__ void k_head(const int* __restrict__ esrc, const int* __restrict__ edst,
                       unsigned* __restrict__ binbuf, int* __restrict__ cntmatT,
                       int* __restrict__ startmatT,
                       const float* __restrict__ X, unsigned short* __restrict__ Xb,
                       const float* __restrict__ W1, const float* __restrict__ W2,
                       unsigned short* __restrict__ Wimg) {
  const int b = blockIdx.x, t = threadIdx.x;

  if (b < RBLK) {
    __shared__ unsigned lbuf[EPB];       // 32 KB
    __shared__ int cnt[NB2];
    __shared__ int base[NB2];
    __shared__ int cur[NB2];
    __shared__ int scanb[512];
    const int e0 = b * EPB;
    const int ne = min(EPB, N_EDGES - e0);

    for (int i = t; i < NB2; i += 512) { cnt[i] = 0; cur[i] = 0; }
    __syncthreads();
    for (int i = t; i < ne; i += 512)
      atomicAdd(&cnt[edst[e0 + i] >> BINSHIFT], 1);
    __syncthreads();
    scanb[t] = (t < NB2) ? cnt[t] : 0;
    __syncthreads();
    for (int d = 1; d < 512; d <<= 1) {
      int x = (t >= d) ? scanb[t - d] : 0;
      __syncthreads();
      scanb[t] += x;
      __syncthreads();
    }
    if (t < NB2) base[t] = scanb[t] - cnt[t];
    __syncthreads();
    for (int i = t; i < ne; i += 512) {
      int d = edst[e0 + i];
      int s = esrc[e0 + i];
      int bi = d >> BINSHIFT;
      int pos = base[bi] + atomicAdd(&cur[bi], 1);
      lbuf[pos] = ((unsigned)(d & 255) << 17) | (unsigned)s;
    }
    __syncthreads();
    // dense stream-out (garbage tail never referenced via counts)
    uint4* dst4 = (uint4*)(binbuf + (size_t)b * EPB);
    const uint4* src4 = (const uint4*)lbuf;
    for (int i = t; i < EPB / 4; i += 512) dst4[i] = src4[i];
    if (t < NB2) {
      cntmatT[t * RBLK + b] = cnt[t];     // [bin][region]
      startmatT[t * RBLK + b] = base[t];
    }
    return;
  }
  if (b < RBLK + HEAD_W_BLOCKS) {
    int bb = b - RBLK;
    const float* W = (bb & 4) ? W2 : W1;
    unsigned short* img = Wimg + ((bb & 4) ? 128 * PADK : 0);
    int k0 = (bb & 3) * 32;
#pragma unroll
    for (int it = 0; it < 8; ++it) {
      int idx = it * 512 + t;                 // 4096 entries: 32 k x 128 n
      int k = k0 + (idx >> 7), n = idx & 127;
      img[n * PADK + k] = f2bf(W[k * 128 + n]);
    }
    return;
  }
  // ---- X f32 -> bf16 ----
  size_t i = ((size_t)(b - RBLK - HEAD_W_BLOCKS) * 512 + t) * 8;
  const float4* p = (const float4*)(X + i);
  float4 a = p[0], c = p[1];
  short8 s;
  s[0] = f2bf(a.x); s[1] = f2bf(a.y); s[2] = f2bf(a.z); s[3] = f2bf(a.w);
  s[4] = f2bf(c.x); s[5] = f2bf(c.y); s[6] = f2bf(c.z); s[7] = f2bf(c.w);
  *(short8*)(Xb + i) = s;
}

// ============ k_sortgather: per-bin sort (LDS-resident) + gather ============
// 391 blocks x 1024 threads, ~46KB LDS -> 2 blocks/CU on all 256 CUs (vs
// round-14's 196 x 82KB = 1/CU on 196 CUs). Block b: gather its bin's ~4096
// edges from 196 region chunks into ebuf, count/scan/scatter to per-node-
// sorted ebuf2 (src only), then 16 waves gather 16 nodes each (8-deep
// unrolled 256B row reads) and write h0 bf16. No global CSR round-trip.
__launch_bounds__(1024)
__global__ void k_sortgather(const unsigned* __restrict__ binbuf,
                             const int* __restrict__ cntmatT,
                             const int* __restrict__ startmatT,
                             const unsigned* __restrict__ X1,
                             unsigned* __restrict__ h0) {
  __shared__ unsigned ebuf[EBUF_CAP];    // 19 KB
  __shared__ unsigned ebuf2[EBUF_CAP];   // 19 KB
  __shared__ int hist[256];
  __shared__ int scn[256];
  __shared__ int nstart[256];
  __shared__ int ncnt[256];
  __shared__ int rcnt[RBLK];
  __shared__ int roff[RBLK];
  __shared__ int eoff[RBLK];
  __shared__ int s_total;

  const int b = blockIdx.x, t = threadIdx.x;
  const int n0 = b << BINSHIFT;
  const int wv = t >> 6, ln = t & 63;

  // this bin's per-region counts/starts (coalesced 784B rows)
  if (t < RBLK) {
    rcnt[t] = cntmatT[b * RBLK + t];
    roff[t] = startmatT[b * RBLK + t];
  }
  __syncthreads();

  // eoff = exclusive scan of rcnt; total = edges in this bin
  if (t < 256) scn[t] = (t < RBLK) ? rcnt[t] : 0;
  __syncthreads();
  for (int d = 1; d < 256; d <<= 1) {
    int x = 0;
    if (t < 256 && t >= d) x = scn[t - d];
    __syncthreads();
    if (t < 256) scn[t] += x;
    __syncthreads();
  }
  if (t < RBLK) eoff[t] = scn[t] - rcnt[t];
  if (t == RBLK - 1) s_total = scn[t];
  __syncthreads();
  const int mytotal = s_total;

  // gather this bin's edges from all regions into LDS (wave wv: r = wv mod 16)
  for (int r = wv; r < RBLK; r += 16) {
    const unsigned* src = binbuf + (size_t)r * EPB + roff[r];
    int c = rcnt[r], o = eoff[r];
    for (int i = ln; i < c; i += 64) ebuf[o + i] = src[i];
  }
  if (t < 256) hist[t] = 0;
  __syncthreads();

  // per-node counts
  for (int i = t; i < mytotal; i += 1024)
    atomicAdd(&hist[ebuf[i] >> 17], 1);
  __syncthreads();
  int v = (t < 256) ? hist[t] : 0;
  if (t < 256) scn[t] = v;
  __syncthreads();
  for (int d = 1; d < 256; d <<= 1) {
    int x = 0;
    if (t < 256 && t >= d) x = scn[t - d];
    __syncthreads();
    if (t < 256) scn[t] += x;
    __syncthreads();
  }
  if (t < 256) {
    nstart[t] = scn[t] - v;
    ncnt[t] = v;
    hist[t] = scn[t] - v;   // write cursor
  }
  __syncthreads();
  // scatter to per-node-sorted order; keep only src (17 bits)
  for (int i = t; i < mytotal; i += 1024) {
    unsigned e = ebuf[i];
    int pos = atomicAdd(&hist[e >> 17], 1);
    ebuf2[pos] = e & 0x1FFFFu;
  }
  __syncthreads();

  // ---- gather phase: wave wv owns local nodes [wv*16, wv*16+16) ----
  for (int j = 0; j < 16; ++j) {
    int li = wv * 16 + j;
    int node = n0 + li;
    if (node >= N_NODES) break;
    unsigned u = X1[(size_t)node * 64 + ln];
    float hx = bflo(u), hy = bfhi(u);
    int e = nstart[li];
    int end = e + ncnt[li];
    for (; e + 8 <= end; e += 8) {
      int s0 = ebuf2[e],     s1 = ebuf2[e + 1], s2 = ebuf2[e + 2], s3 = ebuf2[e + 3];
      int s4 = ebuf2[e + 4], s5 = ebuf2[e + 5], s6 = ebuf2[e + 6], s7 = ebuf2[e + 7];
      unsigned u0 = X1[(size_t)s0 * 64 + ln];
      unsigned u1 = X1[(size_t)s1 * 64 + ln];
      unsigned u2 = X1[(size_t)s2 * 64 + ln];
      unsigned u3 = X1[(size_t)s3 * 64 + ln];
      unsigned u4 = X1[(size_t)s4 * 64 + ln];
      unsigned u5 = X1[(size_t)s5 * 64 + ln];
      unsigned u6 = X1[(size_t)s6 * 64 + ln];
      unsigned u7 = X1[(size_t)s7 * 64 + ln];
      hx += bflo(u0); hy += bfhi(u0);
      hx += bflo(u1); hy += bfhi(u1);
      hx += bflo(u2); hy += bfhi(u2);
      hx += bflo(u3); hy += bfhi(u3);
      hx += bflo(u4); hy += bfhi(u4);
      hx += bflo(u5); hy += bfhi(u5);
      hx += bflo(u6); hy += bfhi(u6);
      hx += bflo(u7); hy += bfhi(u7);
    }
    for (; e + 2 <= end; e += 2) {
      unsigned u0 = X1[(size_t)ebuf2[e] * 64 + ln];
      unsigned u1 = X1[(size_t)ebuf2[e + 1] * 64 + ln];
      hx += bflo(u0); hy += bfhi(u0);
      hx += bflo(u1); hy += bfhi(u1);
    }
    for (; e < end; ++e) {
      unsigned u0 = X1[(size_t)ebuf2[e] * 64 + ln];
      hx += bflo(u0); hy += bfhi(u0);
    }
    h0[(size_t)node * 64 + ln] = ((unsigned)f2bf(hy) << 16) | f2bf(hx);
  }
}

// ============ k_mlp2: BR=128, 8 waves (wave owns 16 rows), 2 blocks/CU ======
// (round-7/10/11/14 proven) W1 staged in LDS; restage W2 after GEMM1.
#define BR2 128

__launch_bounds__(512, 4)
__global__ void k_mlp2(const unsigned short* __restrict__ h0,
                       const unsigned short* __restrict__ Wimg,
                       const float* __restrict__ b1v, const float* __restrict__ b2v,
                       float* __restrict__ out) {
  __shared__ __attribute__((aligned(16))) unsigned short lW[128 * PADK];
  __shared__ __attribute__((aligned(16))) unsigned short lH[BR2 * PADK];

  const int t = threadIdx.x;
  const int wave = t >> 6, lane = t & 63;
  const int lr = lane & 15, lg = lane >> 4;
  const int row0 = blockIdx.x * BR2;
  const int wrow = row0 + wave * 16;

  const uint4* wi = (const uint4*)Wimg;
  uint4* lw = (uint4*)lW;

  // stage W1 image (2176 uint4)
  for (int i = t; i < 2176; i += 512) lw[i] = wi[i];

  // A fragments from global bf16 h0
  bf16x8 a[4];
#pragma unroll
  for (int kb = 0; kb < 4; ++kb) {
    int r = wrow + lr;
    if (r >= N_NODES) r = N_NODES - 1;          // clamp; result unused
    a[kb] = __builtin_bit_cast(bf16x8,
        *(const short8*)(h0 + (size_t)r * D + kb * 32 + lg * 8));
  }

  f32x4 acc[8];
#pragma unroll
  for (int nc = 0; nc < 8; ++nc) {
    float bb = b1v[nc * 16 + lr];
    acc[nc] = (f32x4){bb, bb, bb, bb};
  }

  __syncthreads();   // W1 staged

  // GEMM1
#pragma unroll
  for (int nc = 0; nc < 8; ++nc) {
#pragma unroll
    for (int kb = 0; kb < 4; ++kb) {
      bf16x8 b = *(const bf16x8*)&lW[(nc * 16 + lr) * PADK + kb * 32 + lg * 8];
      acc[nc] = __builtin_amdgcn_mfma_f32_16x16x32_bf16(a[kb], b, acc[nc], 0, 0, 0);
    }
  }

  __syncthreads();   // everyone done reading W1

  // restage W2
  {
    const uint4* wi2 = (const uint4*)Wimg + 2176;
    for (int i = t; i < 2176; i += 512) lw[i] = wi2[i];
  }

  // ReLU -> h1 into own stripe (intra-wave dependency only)
#pragma unroll
  for (int nc = 0; nc < 8; ++nc) {
#pragma unroll
    for (int r = 0; r < 4; ++r) {
      float v = acc[nc][r];
      v = v > 0.f ? v : 0.f;
      lH[(wave * 16 + lg * 4 + r) * PADK + nc * 16 + lr] = f2bf(v);
    }
  }

  __syncthreads();   // W2 staged

  bf16x8 a2[4];
#pragma unroll
  for (int kb = 0; kb < 4; ++kb)
    a2[kb] = *(const bf16x8*)&lH[(wave * 16 + lr) * PADK + kb * 32 + lg * 8];

#pragma unroll
  for (int nc = 0; nc < 8; ++nc) {
    float bb = b2v[nc * 16 + lr];
    acc[nc] = (f32x4){bb, bb, bb, bb};
  }

  // GEMM2
#pragma unroll
  for (int nc = 0; nc < 8; ++nc) {
#pragma unroll
    for (int kb = 0; kb < 4; ++kb) {
      bf16x8 b = *(const bf16x8*)&lW[(nc * 16 + lr) * PADK + kb * 32 + lg * 8];
      acc[nc] = __builtin_amdgcn_mfma_f32_16x16x32_bf16(a2[kb], b, acc[nc], 0, 0, 0);
    }
  }

  // store f32
#pragma unroll
  for (int nc = 0; nc < 8; ++nc) {
#pragma unroll
    for (int r = 0; r < 4; ++r) {
      int row = wrow + lg * 4 + r;
      if (row < N_NODES) out[(size_t)row * D + nc * 16 + lr] = acc[nc][r];
    }
  }
}

// ================= old CSR build (fallback path, end-semantics offs) ========

__global__ void k_hist(const int* __restrict__ dst, int* __restrict__ deg) {
  int i = blockIdx.x * 256 + threadIdx.x;
  if (i < N_EDGES) atomicAdd(&deg[dst[i]], 1);
}

__global__ void k_scan1(const int* __restrict__ deg, int* __restrict__ offs,
                        int* __restrict__ bsum) {
  __shared__ int s[1024];
  int t = threadIdx.x;
  int i = blockIdx.x * 1024 + t;
  int v = (i < N_NODES) ? deg[i] : 0;
  s[t] = v;
  __syncthreads();
  for (int d = 1; d < 1024; d <<= 1) {
    int x = (t >= d) ? s[t - d] : 0;
    __syncthreads();
    s[t] += x;
    __syncthreads();
  }
  if (i < N_NODES) offs[i] = s[t] - v;
  if (t == 1023) bsum[blockIdx.x] = s[t];
}

__global__ void k_scan2(int* __restrict__ bsum) {
  __shared__ int s[128];
  int t = threadIdx.x;
  int v = (t < 98) ? bsum[t] : 0;
  s[t] = v;
  __syncthreads();
  for (int d = 1; d < 128; d <<= 1) {
    int x = (t >= d) ? s[t - d] : 0;
    __syncthreads();
    s[t] += x;
    __syncthreads();
  }
  if (t < 98) bsum[t] = s[t] - v;
}

__global__ void k_scan3(int* __restrict__ offs, const int* __restrict__ bsum) {
  int i = blockIdx.x * 1024 + threadIdx.x;
  if (i < N_NODES) offs[i] += bsum[blockIdx.x];
}

__global__ void k_bucket(const int* __restrict__ src, const int* __restrict__ dst,
                         int* __restrict__ offs, int* __restrict__ srt) {
  int i = blockIdx.x * 256 + threadIdx.x;
  if (i < N_EDGES) {
    int pos = atomicAdd(&offs[dst[i]], 1);
    srt[pos] = src[i];
  }
}

// ------------- f32 fallback gather (END-semantics offs) -------------
__global__ void k_gather(const float* __restrict__ X, const int* __restrict__ deg,
                         const int* __restrict__ offs, const int* __restrict__ srt,
                         float* __restrict__ out) {
  int node = blockIdx.x * 4 + (threadIdx.x >> 6);
  int lane = threadIdx.x & 63;
  const float2* X2 = (const float2*)X;
  float2 h = X2[(size_t)node * 64 + lane];
  int end = offs[node];
  int dg = deg[node];
  for (int e = end - dg; e < end; ++e) {
    int s = srt[e];
    float2 x = X2[(size_t)s * 64 + lane];
    h.x += x.x; h.y += x.y;
  }
  ((float2*)out)[(size_t)node * 64 + lane] = h;
}

// ------------- fallback fused MLP (f32 h0 in d_out, in-place) -------------
#define BR 256

__launch_bounds__(512, 1)
__global__ void k_mlp(const float* __restrict__ h0,
                      const float* __restrict__ W1, const float* __restrict__ b1,
                      const float* __restrict__ W2, const float* __restrict__ b2,
                      float* __restrict__ out) {
  __shared__ __attribute__((aligned(16))) unsigned short lW[2 * 128 * PADK];
  __shared__ __attribute__((aligned(16))) unsigned short lH[BR * PADK];

  const int t = threadIdx.x;
  const int wave = t >> 6, lane = t & 63;
  const int lr = lane & 15, lg = lane >> 4;
  const int row0 = blockIdx.x * BR;
  const int wrow = row0 + wave * 32;

  for (int i = t; i < 128 * 128; i += 512) {
    int k = i >> 7, n = i & 127;
    lW[n * PADK + k] = f2bf(W1[i]);
    lW[128 * PADK + n * PADK + k] = f2bf(W2[i]);
  }

  bf16x8 a[2][4];
#pragma unroll
  for (int tr = 0; tr < 2; ++tr) {
#pragma unroll
    for (int kb = 0; kb < 4; ++kb) {
      int r = wrow + tr * 16 + lr;
      if (r >= N_NODES) r = N_NODES - 1;
      const float4* p = (const float4*)(h0 + (size_t)r * D + kb * 32 + lg * 8);
      float4 f0 = p[0], f1 = p[1];
      short8 s;
      s[0] = f2bf(f0.x); s[1] = f2bf(f0.y); s[2] = f2bf(f0.z); s[3] = f2bf(f0.w);
      s[4] = f2bf(f1.x); s[5] = f2bf(f1.y); s[6] = f2bf(f1.z); s[7] = f2bf(f1.w);
      a[tr][kb] = __builtin_bit_cast(bf16x8, s);
    }
  }

  f32x4 acc[2][8];
#pragma unroll
  for (int nc = 0; nc < 8; ++nc) {
    float bb = b1[nc * 16 + lr];
#pragma unroll
    for (int tr = 0; tr < 2; ++tr) acc[tr][nc] = (f32x4){bb, bb, bb, bb};
  }

  __syncthreads();

#pragma unroll
  for (int nc = 0; nc < 8; ++nc) {
#pragma unroll
    for (int kb = 0; kb < 4; ++kb) {
      bf16x8 b = *(const bf16x8*)&lW[(nc * 16 + lr) * PADK + kb * 32 + lg * 8];
#pragma unroll
      for (int tr = 0; tr < 2; ++tr)
        acc[tr][nc] = __builtin_amdgcn_mfma_f32_16x16x32_bf16(a[tr][kb], b, acc[tr][nc], 0, 0, 0);
    }
  }

#pragma unroll
  for (int tr = 0; tr < 2; ++tr) {
#pragma unroll
    for (int nc = 0; nc < 8; ++nc) {
#pragma unroll
      for (int r = 0; r < 4; ++r) {
        float v = acc[tr][nc][r];
        v = v > 0.f ? v : 0.f;
        int lrow = wave * 32 + tr * 16 + lg * 4 + r;
        lH[lrow * PADK + nc * 16 + lr] = f2bf(v);
      }
    }
  }

  __syncthreads();

  bf16x8 a2[2][4];
#pragma unroll
  for (int tr = 0; tr < 2; ++tr) {
#pragma unroll
    for (int kb = 0; kb < 4; ++kb)
      a2[tr][kb] = *(const bf16x8*)&lH[(wave * 32 + tr * 16 + lr) * PADK + kb * 32 + lg * 8];
  }

#pragma unroll
  for (int nc = 0; nc < 8; ++nc) {
    float bb = b2[nc * 16 + lr];
#pragma unroll
    for (int tr = 0; tr < 2; ++tr) acc[tr][nc] = (f32x4){bb, bb, bb, bb};
  }

#pragma unroll
  for (int nc = 0; nc < 8; ++nc) {
#pragma unroll
    for (int kb = 0; kb < 4; ++kb) {
      bf16x8 b = *(const bf16x8*)&lW[128 * PADK + (nc * 16 + lr) * PADK + kb * 32 + lg * 8];
#pragma unroll
      for (int tr = 0; tr < 2; ++tr)
        acc[tr][nc] = __builtin_amdgcn_mfma_f32_16x16x32_bf16(a2[tr][kb], b, acc[tr][nc], 0, 0, 0);
    }
  }

#pragma unroll
  for (int tr = 0; tr < 2; ++tr) {
#pragma unroll
    for (int nc = 0; nc < 8; ++nc) {
#pragma unroll
      for (int r = 0; r < 4; ++r) {
        int row = wrow + tr * 16 + lg * 4 + r;
        if (row < N_NODES) out[(size_t)row * D + nc * 16 + lr] = acc[tr][nc][r];
      }
    }
  }
}

extern "C" void kernel_launch(void* const* d_in, const int* in_sizes, int n_in,
                              void* d_out, int out_size, void* d_ws, size_t ws_size,
                              hipStream_t stream) {
  const float* X  = (const float*)d_in[0];
  const float* W1 = (const float*)d_in[1];
  const float* b1 = (const float*)d_in[2];
  const float* W2 = (const float*)d_in[3];
  const float* b2 = (const float*)d_in[4];
  const int* esrc = (const int*)d_in[5];
  const int* edst = (const int*)d_in[6];
  float* out = (float*)d_out;

  char* ws = (char*)d_ws;
  // primary layout — NO aliasing. cntmat/startmat are 391x196 ints now.
  // NEED = 58,305,280 <= proven 58,471,680 budget.
  unsigned* binbuf = (unsigned*)(ws);                        // 6,422,528 B
  int* cntmatT   = (int*)(ws + 6422528);                     // 306,560 B
  int* startmatT = (int*)(ws + 6729088);                     // 306,560 B
  unsigned short* Xb  = (unsigned short*)(ws + 7035648);     // 25.6 MB
  unsigned short* h0b = (unsigned short*)(ws + 32635648);    // 25.6 MB
  unsigned short* Wimg = (unsigned short*)(ws + 58235648);   // 69,632 B
  const size_t NEED = 58305280;

  if (ws_size >= NEED) {
    k_head<<<RBLK + HEAD_W_BLOCKS + HEAD_CVT_BLOCKS, 512, 0, stream>>>(
        esrc, edst, binbuf, cntmatT, startmatT, X, Xb, W1, W2, Wimg);
    k_sortgather<<<NB2, 1024, 0, stream>>>(binbuf, cntmatT, startmatT,
                                           (const unsigned*)Xb, (unsigned*)h0b);
    k_mlp2<<<(N_NODES + BR2 - 1) / BR2, 512, 0, stream>>>(h0b, Wimg, b1, b2, out);
  } else {
    // fallback: proven round-1 pipeline (f32 gather, END-semantics offs)
    int* deg  = (int*)(ws);                    // 400,000 B
    int* offs = (int*)(ws + 400000);           // 400,000 B
    int* bsum = (int*)(ws + 800000);           // 1 KB
    int* srtF = (int*)(ws + 802048);           // 6.4 MB
    hipMemsetAsync(deg, 0, N_NODES * sizeof(int), stream);
    k_hist  <<<N_EDGES / 256, 256, 0, stream>>>(edst, deg);
    k_scan1 <<<98, 1024, 0, stream>>>(deg, offs, bsum);
    k_scan2 <<<1, 128, 0, stream>>>(bsum);
    k_scan3 <<<98, 1024, 0, stream>>>(offs, bsum);
    k_bucket<<<N_EDGES / 256, 256, 0, stream>>>(esrc, edst, offs, srtF);
    k_gather<<<N_NODES / 4, 256, 0, stream>>>(X, deg, offs, srtF, out);
    k_mlp   <<<(N_NODES + BR - 1) / BR, 512, 0, stream>>>(out, W1, b1, W2, b2, out);
  }
}